// Round 7
// baseline (707.699 us; speedup 1.0000x reference)
//
#include <hip/hip_runtime.h>
#include <hip/hip_bf16.h>
#include <cstdint>

typedef __hip_bfloat16 bf16;
#define CDIV(a,b) (((a)+(b)-1)/(b))

typedef __attribute__((ext_vector_type(8))) short short8;
typedef __attribute__((ext_vector_type(8))) unsigned short usht8;
typedef __attribute__((ext_vector_type(4))) float f32x4v;

struct us4 { unsigned short x, y, z, w; };

// ---------------- device helpers ----------------
__device__ __forceinline__ float lrelu02(float x) { return fmaxf(x, 0.f) + 0.2f * fminf(x, 0.f); }

__device__ __forceinline__ float b2f(unsigned short u) {
    return __uint_as_float((unsigned)u << 16);
}
// f32 -> bf16 bits, round-to-nearest-even
__device__ __forceinline__ unsigned short f2b(float f) {
    unsigned u = __float_as_uint(f);
    unsigned r = u + 0x7FFFu + ((u >> 16) & 1u);
    return (unsigned short)(r >> 16);
}

// swizzled LDS index (ushort units) for [row][32] tiles, 8-elem granularity
__device__ __forceinline__ int swz(int row, int kg) {
    return row * 32 + (kg ^ ((row >> 1) & 3)) * 8;
}

// ---------------- fill ----------------
__global__ void fill_i32(int* __restrict__ p, int v, long n) {
    long i = (long)blockIdx.x * blockDim.x + threadIdx.x;
    long st = (long)gridDim.x * blockDim.x;
    for (; i < n; i += st) p[i] = v;
}

// ---------------- CSR build (both directions fused) ----------------
__global__ void hist2_kernel(const int* __restrict__ edm, const int* __restrict__ edu,
                             int* __restrict__ deg_m, int* __restrict__ deg_u, int E) {
    int e = blockIdx.x * blockDim.x + threadIdx.x;
    if (e < E) atomicAdd(&deg_m[edm[e]], 1);
    else if (e < 2 * E) atomicAdd(&deg_u[edu[e - E]], 1);
}

#define SCAN_T 256
#define SCAN_E 16
__global__ void __launch_bounds__(SCAN_T) scan1_dual_kernel(
    const int* __restrict__ deg0, int* __restrict__ off0, int* __restrict__ bsum0, int n0,
    const int* __restrict__ deg1, int* __restrict__ off1, int* __restrict__ bsum1, int n1)
{
    const int* deg = blockIdx.y ? deg1 : deg0;
    int* off  = blockIdx.y ? off1 : off0;
    int* bsum = blockIdx.y ? bsum1 : bsum0;
    const int n = blockIdx.y ? n1 : n0;

    __shared__ int lds[SCAN_T];
    const int tb = blockIdx.x * (SCAN_T * SCAN_E) + threadIdx.x * SCAN_E;
    int v[SCAN_E];
    int tot = 0;
#pragma unroll
    for (int j = 0; j < SCAN_E; ++j) {
        v[j] = (tb + j < n) ? deg[tb + j] : 0;
        tot += v[j];
    }
    lds[threadIdx.x] = tot;
    __syncthreads();
    for (int s = 1; s < SCAN_T; s <<= 1) {
        int t = (threadIdx.x >= s) ? lds[threadIdx.x - s] : 0;
        __syncthreads();
        lds[threadIdx.x] += t;
        __syncthreads();
    }
    int run = (threadIdx.x > 0) ? lds[threadIdx.x - 1] : 0;
#pragma unroll
    for (int j = 0; j < SCAN_E; ++j) {
        if (tb + j < n) off[tb + j] = run;
        run += v[j];
    }
    if (threadIdx.x == SCAN_T - 1) bsum[blockIdx.x] = lds[SCAN_T - 1];
}
__global__ void scan2_dual_kernel(int* __restrict__ bm, int nbm, int* __restrict__ bu, int nbu) {
    int t = threadIdx.x & 63;
    int* b = (threadIdx.x >= 64) ? bu : bm;
    int nb = (threadIdx.x >= 64) ? nbu : nbm;
    int orig = (t < nb) ? b[t] : 0;
    int v = orig;
    for (int s = 1; s < 64; s <<= 1) {
        int u = __shfl_up(v, s);
        if (t >= s) v += u;
    }
    if (t < nb) b[t] = v - orig;
}
__global__ void scan3_dual_kernel(int* __restrict__ off0, const int* __restrict__ bsum0, int n0,
                                  int* __restrict__ off1, const int* __restrict__ bsum1, int n1) {
    int* off = blockIdx.y ? off1 : off0;
    const int* bsum = blockIdx.y ? bsum1 : bsum0;
    const int n = blockIdx.y ? n1 : n0;
    int i = blockIdx.x * blockDim.x + threadIdx.x;
    if (i < n) off[i] += bsum[i / (SCAN_T * SCAN_E)];
}

__global__ void csr_fill2_kernel(
    const int* __restrict__ esm, const int* __restrict__ edm, const float* __restrict__ eam,
    const int* __restrict__ offm, int* __restrict__ curm, int2* __restrict__ recm,
    const int* __restrict__ esu, const int* __restrict__ edu, const float* __restrict__ eau,
    const int* __restrict__ offu, int* __restrict__ curu, int2* __restrict__ recu, int E)
{
    int e = blockIdx.x * blockDim.x + threadIdx.x;
    if (e < E) {
        int d = edm[e];
        int r = atomicAdd(&curm[d], 1);
        int2 q; q.x = esm[e]; q.y = __float_as_int(eam[e]);
        recm[offm[d] + r] = q;
    } else if (e < 2 * E) {
        e -= E;
        int d = edu[e];
        int r = atomicAdd(&curu[d], 1);
        int2 q; q.x = esu[e]; q.y = __float_as_int(eau[e]);
        recu[offu[d] + r] = q;
    }
}

// ---------------- weight transpose+convert: W[K][N] f32 -> Wt[N][K] bf16 ----
struct TxArgs {
    const float* src[4];
    unsigned short* dst[4];
};
__global__ void txp_kernel(TxArgs a) {
    const int m = blockIdx.y;
    const int K = 256, N = 256;
    const long total = (long)K * N;
    const float* __restrict__ s = a.src[m];
    unsigned short* __restrict__ d = a.dst[m];
    for (long i = (long)blockIdx.x * blockDim.x + threadIdx.x; i < total;
         i += (long)gridDim.x * blockDim.x) {
        int k = (int)(i >> 8), nn = (int)(i & 255);
        d[(long)nn * K + k] = f2b(s[i]);
    }
}

// ---------------- combine phase-0 + layer-0 weights (all affine) ----------
// Wc[k,n] = sum_c Wu[k][c] * Wsrc[c][n'];  bc[n] = sum_c bu[c]*Wsrc[c][n'] + bsrc[n']
// n<256 -> (Wa,ba), else (Wb,bb). Output transposed bf16 wt[512][64] + f32 bc[512].
__global__ void cw_kernel(const float* __restrict__ Wu, const float* __restrict__ bu,
                          const float* __restrict__ Wa, const float* __restrict__ ba,
                          const float* __restrict__ Wb, const float* __restrict__ bb,
                          unsigned short* __restrict__ wt, float* __restrict__ bc)
{
    int tid = blockIdx.x * blockDim.x + threadIdx.x;
    if (tid < 512 * 64) {
        int nn = tid >> 6, k = tid & 63;
        const float* Ws = (nn < 256) ? Wa : Wb;
        int nc = nn & 255;
        float s = 0.f;
        for (int c = 0; c < 64; ++c) s = fmaf(Wu[k * 64 + c], Ws[c * 256 + nc], s);
        wt[nn * 64 + k] = f2b(s);
    } else if (tid < 512 * 64 + 512) {
        int nn = tid - 512 * 64;
        const float* Ws = (nn < 256) ? Wa : Wb;
        const float* bs = (nn < 256) ? ba : bb;
        int nc = nn & 255;
        float s = bs[nc];
        for (int c = 0; c < 64; ++c) s = fmaf(bu[c], Ws[c * 256 + nc], s);
        bc[nn] = s;
    }
}

// ---------------- MFMA GEMM with split N output ----------------
// Y1 gets cols [0,N/2), Y2 gets cols [N/2,N); separate biases.
template<int K, int N, bool GATHER>
__global__ void __launch_bounds__(256) gemm_split_kernel(
    const void* __restrict__ Asrc, const int* __restrict__ ids,
    const unsigned short* __restrict__ Wt,
    const float* __restrict__ bias1, const float* __restrict__ bias2,
    unsigned short* __restrict__ Y1, unsigned short* __restrict__ Y2, int n)
{
    constexpr int NH = N / 2;
    constexpr int NCT = N / 64;
    const int t = threadIdx.x;
    const int wid = t >> 6, lane = t & 63;
    const int row0 = blockIdx.x * 64;

    __shared__ unsigned short As[64 * 32];
    __shared__ unsigned short Ws[N * 32];

    f32x4v acc[4][NCT];
#pragma unroll
    for (int rt = 0; rt < 4; ++rt)
#pragma unroll
        for (int ct = 0; ct < NCT; ++ct) acc[rt][ct] = (f32x4v){0.f, 0.f, 0.f, 0.f};

    const int r_st = t >> 2, kg_st = t & 3;
    const int grow = row0 + r_st;
    long abase = 0;
    if (grow < n) abase = GATHER ? (long)ids[grow] * K : (long)grow * K;

    for (int kt = 0; kt < K / 32; ++kt) {
        usht8 av = (usht8)0;
        if (grow < n) {
            if (GATHER) {
                const float* p = (const float*)Asrc + abase + kt * 32 + kg_st * 8;
#pragma unroll
                for (int j = 0; j < 8; ++j) av[j] = f2b(p[j]);
            } else {
                av = *(const usht8*)((const unsigned short*)Asrc + abase + kt * 32 + kg_st * 8);
            }
        }
        *(usht8*)&As[swz(r_st, kg_st)] = av;
#pragma unroll
        for (int i = 0; i < NCT; ++i) {
            int idx = t + i * 256;
            int c = idx >> 2, kg = idx & 3;
            *(usht8*)&Ws[swz(c, kg)] = *(const usht8*)&Wt[(long)c * K + kt * 32 + kg * 8];
        }
        __syncthreads();

        const int kgrp = lane >> 4;
        short8 af[4];
#pragma unroll
        for (int rt = 0; rt < 4; ++rt)
            af[rt] = *(const short8*)&As[swz(rt * 16 + (lane & 15), kgrp)];
#pragma unroll
        for (int ct = 0; ct < NCT; ++ct) {
            int col = wid * (N / 4) + ct * 16 + (lane & 15);
            short8 bfr = *(const short8*)&Ws[swz(col, kgrp)];
#pragma unroll
            for (int rt = 0; rt < 4; ++rt)
                acc[rt][ct] = __builtin_amdgcn_mfma_f32_16x16x32_bf16(af[rt], bfr, acc[rt][ct], 0, 0, 0);
        }
        __syncthreads();
    }

#pragma unroll
    for (int ct = 0; ct < NCT; ++ct) {
        int col = wid * (N / 4) + ct * 16 + (lane & 15);
        const bool hi = col >= NH;
        unsigned short* __restrict__ Y = hi ? Y2 : Y1;
        const float* __restrict__ bs = hi ? bias2 : bias1;
        int cl = hi ? col - NH : col;
        float bb = bs[cl];
#pragma unroll
        for (int rt = 0; rt < 4; ++rt) {
#pragma unroll
            for (int j = 0; j < 4; ++j) {
                int row = row0 + rt * 16 + (lane >> 4) * 4 + j;
                if (row < n) Y[(long)row * NH + cl] = f2b(acc[rt][ct][j] + bb);
            }
        }
    }
}

// ---------------- fused GATv2 layer (head-split lanes, R5 structure) ------
// lane = h*16 + q; lane owns channels c = h*64 + q*4 .. +3
// one wave per destination; 4-edge batches for load ILP; branchless online
// softmax; record broadcasts via v_readlane (uniform index -> SGPR)
template<bool CONCAT>
__global__ void __launch_bounds__(256) gat_fused_kernel(
    const int* __restrict__ deg, const int* __restrict__ off,
    const int2* __restrict__ rec,
    const bf16* __restrict__ xl, const bf16* __restrict__ xr,
    const float* __restrict__ We, const float* __restrict__ att,
    const float* __restrict__ bias,
    const float* __restrict__ g, const float* __restrict__ be,
    void* __restrict__ yout, int n)
{
    const int lane = threadIdx.x & 63;
    const int d = blockIdx.x * 4 + (threadIdx.x >> 6);
    if (d >= n) return;
    const int q = lane & 15;
    const int c0 = ((lane >> 4) << 6) + (q << 2);   // h*64 + q*4

    float4 We4 = *(const float4*)(We + c0);
    float4 att4 = *(const float4*)(att + c0);
    us4 xrv = *(const us4*)((const unsigned short*)xr + (long)d * 256 + c0);
    float xr4[4] = {b2f(xrv.x), b2f(xrv.y), b2f(xrv.z), b2f(xrv.w)};

    float m = -1e30f, den = 0.f;
    float acc[4] = {0.f, 0.f, 0.f, 0.f};

    const int dg = deg[d], o0 = off[d];
    const unsigned short* __restrict__ xlp = (const unsigned short*)xl;

    for (int base = 0; base < dg; base += 64) {
        int2 r;
        if (base + lane < dg) r = rec[o0 + base + lane];
        else { r.x = 0; r.y = 0; }
        const int cnt = min(dg - base, 64);
        for (int j = 0; j < cnt; j += 4) {
            int sA[4], aB[4];
            us4 xvA[4];
#pragma unroll
            for (int u = 0; u < 4; ++u) {
                sA[u] = __builtin_amdgcn_readlane(r.x, j + u);   // SGPR broadcast
                aB[u] = __builtin_amdgcn_readlane(r.y, j + u);
            }
#pragma unroll
            for (int u = 0; u < 4; ++u)
                xvA[u] = *(const us4*)(xlp + (long)sA[u] * 256 + c0);
#pragma unroll
            for (int u = 0; u < 4; ++u) {
                const float a = __int_as_float(aB[u]);
                float xv[4] = {b2f(xvA[u].x), b2f(xvA[u].y), b2f(xvA[u].z), b2f(xvA[u].w)};
                float part = 0.f;
#pragma unroll
                for (int i = 0; i < 4; ++i) {
                    float t = xv[i] + fmaf(a, (&We4.x)[i], xr4[i]);
                    part = fmaf(lrelu02(t), (&att4.x)[i], part);
                }
                // reduce over the 16-lane head group (all 4 heads in parallel)
#pragma unroll
                for (int st = 1; st < 16; st <<= 1) part += __shfl_xor(part, st);
                float l = (j + u < cnt) ? part : -1e30f;
                float mn = fmaxf(m, l);
                float sc = __expf(m - mn);
                float p  = __expf(l - mn);
                m = mn;
                den = fmaf(den, sc, p);
#pragma unroll
                for (int i = 0; i < 4; ++i) acc[i] = fmaf(acc[i], sc, p * xv[i]);
            }
        }
    }

    const float id = 1.f / (den + 1e-16f);
    if (CONCAT) {
        float4 bi = *(const float4*)(bias + c0);
        float v[4], s1 = 0.f, s2 = 0.f;
#pragma unroll
        for (int i = 0; i < 4; ++i) {
            v[i] = fmaf(acc[i], id, (&bi.x)[i]);
            s1 += v[i]; s2 = fmaf(v[i], v[i], s2);
        }
#pragma unroll
        for (int st = 1; st < 64; st <<= 1) {
            s1 += __shfl_xor(s1, st);
            s2 += __shfl_xor(s2, st);
        }
        float mean = s1 * (1.f / 256.f);
        float var = s2 * (1.f / 256.f) - mean * mean;
        float rr = rsqrtf(var + 1e-5f);
        float4 gg = *(const float4*)(g + c0);
        float4 bb = *(const float4*)(be + c0);
        us4 o;
        o.x = f2b(lrelu02(fmaf((&gg.x)[0] * rr, v[0] - mean, (&bb.x)[0])));
        o.y = f2b(lrelu02(fmaf((&gg.x)[1] * rr, v[1] - mean, (&bb.x)[1])));
        o.z = f2b(lrelu02(fmaf((&gg.x)[2] * rr, v[2] - mean, (&bb.x)[2])));
        o.w = f2b(lrelu02(fmaf((&gg.x)[3] * rr, v[3] - mean, (&bb.x)[3])));
        *(us4*)((unsigned short*)yout + (long)d * 256 + c0) = o;
    } else {
        float vh[4];
#pragma unroll
        for (int i = 0; i < 4; ++i) vh[i] = acc[i] * id;
        // sum over the 4 head groups (lanes differing in bits 4,5)
#pragma unroll
        for (int st = 16; st < 64; st <<= 1)
#pragma unroll
            for (int i = 0; i < 4; ++i) vh[i] += __shfl_xor(vh[i], st);
        const int oc = q << 2;
        float4 bi = *(const float4*)(bias + oc);
        float v[4], s1 = 0.f, s2 = 0.f;
#pragma unroll
        for (int i = 0; i < 4; ++i) {
            v[i] = fmaf(0.25f, vh[i], (&bi.x)[i]);
            s1 += v[i]; s2 = fmaf(v[i], v[i], s2);
        }
#pragma unroll
        for (int st = 1; st < 16; st <<= 1) {
            s1 += __shfl_xor(s1, st);
            s2 += __shfl_xor(s2, st);
        }
        float mean = s1 * (1.f / 64.f);
        float var = s2 * (1.f / 64.f) - mean * mean;
        float rr = rsqrtf(var + 1e-5f);
        float4 gg = *(const float4*)(g + oc);
        float4 bb = *(const float4*)(be + oc);
        if (lane < 16) {
            float4 o;
            o.x = lrelu02(fmaf((&gg.x)[0] * rr, v[0] - mean, (&bb.x)[0]));
            o.y = lrelu02(fmaf((&gg.x)[1] * rr, v[1] - mean, (&bb.x)[1]));
            o.z = lrelu02(fmaf((&gg.x)[2] * rr, v[2] - mean, (&bb.x)[2]));
            o.w = lrelu02(fmaf((&gg.x)[3] * rr, v[3] - mean, (&bb.x)[3]));
            *(float4*)((float*)yout + (long)d * 64 + oc) = o;
        }
    }
}

// ---------------- host orchestration ----------------
extern "C" void kernel_launch(void* const* d_in, const int* in_sizes, int n_in,
                              void* d_out, int out_size, void* d_ws, size_t ws_size,
                              hipStream_t stream)
{
    auto F = [&](int i) { return (const float*)d_in[i]; };
    auto I = [&](int i) { return (const int*)d_in[i]; };

    const int NU = in_sizes[0];
    const int NM = in_sizes[1];
    const int E  = in_sizes[2] / 2;

    const int* user_ids  = I(0);
    const int* movie_ids = I(1);
    const int* ei_um = I(2);
    const int* ei_mu = I(3);
    const float* ea_um = F(4);
    const float* ea_mu = F(5);
    const float* user_emb  = F(6);
    const float* movie_emb = F(7);
    const float* W_user = F(8),  *b_user = F(9);
    const float* W_movie = F(10), *b_movie = F(11);
    const int L0UM = 12, L0MU = 19, L1UM = 26, L1MU = 33;
    const float* g0u = F(40), *be0u = F(41);
    const float* g0m = F(42), *be0m = F(43);
    const float* g1u = F(44), *be1u = F(45);
    const float* g1m = F(46), *be1m = F(47);

    // ---- workspace layout ----
    char* w = (char*)d_ws;
    size_t off = 0;
    auto alloc = [&](size_t bytes) -> void* {
        void* p = w + off;
        off = (off + bytes + 255) & ~(size_t)255;
        return p;
    };
    bf16* UB1 = (bf16*)alloc((size_t)NU * 256 * 2);
    bf16* UB2 = (bf16*)alloc((size_t)NU * 256 * 2);
    bf16* UB3 = (bf16*)alloc((size_t)NU * 256 * 2);
    bf16* MB1 = (bf16*)alloc((size_t)NM * 256 * 2);
    bf16* MB2 = (bf16*)alloc((size_t)NM * 256 * 2);
    bf16* MB3 = (bf16*)alloc((size_t)NM * 256 * 2);
    // deg/cur contiguous for one fill
    int* degcur = (int*)alloc((size_t)2 * (NM + NU) * 4);
    int* deg_m = degcur;
    int* deg_u = degcur + NM;
    int* cur_m = degcur + NM + NU;
    int* cur_u = degcur + 2 * NM + NU;
    int* off_m = (int*)alloc((size_t)NM * 4);
    int* off_u = (int*)alloc((size_t)NU * 4);
    int2* rec_m = (int2*)alloc((size_t)(E + 4) * 8);
    int2* rec_u = (int2*)alloc((size_t)(E + 4) * 8);
    int* bsum_m = (int*)alloc(64 * 4);
    int* bsum_u = (int*)alloc(64 * 4);
    // layer-1 transposed weights: adjacency gives the N=512 concatenation
    unsigned short* wt_l1um_l = (unsigned short*)alloc(256 * 256 * 2);  // user pair lo
    unsigned short* wt_l1mu_r = (unsigned short*)alloc(256 * 256 * 2);  // user pair hi
    unsigned short* wt_l1um_r = (unsigned short*)alloc(256 * 256 * 2);  // movie pair lo
    unsigned short* wt_l1mu_l = (unsigned short*)alloc(256 * 256 * 2);  // movie pair hi
    // combined layer-0 weights (phase-0 folded in)
    unsigned short* wt_c_user  = (unsigned short*)alloc(512 * 64 * 2);
    unsigned short* wt_c_movie = (unsigned short*)alloc(512 * 64 * 2);
    float* bc_user  = (float*)alloc(512 * 4);
    float* bc_movie = (float*)alloc(512 * 4);
    if (off > ws_size) return;

    float* out_u = (float*)d_out;
    float* out_m = out_u + (size_t)NU * 64;

    const int FB = 256;

    // ---- weight prep ----
    TxArgs tx;
    tx.src[0] = F(L1UM+0); tx.dst[0] = wt_l1um_l;
    tx.src[1] = F(L1MU+2); tx.dst[1] = wt_l1mu_r;
    tx.src[2] = F(L1UM+2); tx.dst[2] = wt_l1um_r;
    tx.src[3] = F(L1MU+0); tx.dst[3] = wt_l1mu_l;
    txp_kernel<<<dim3(64, 4), 256, 0, stream>>>(tx);
    // user: cols 0-255 = W_user@l0um_Wl (xl_u0), 256-511 = W_user@l0mu_Wr (xr_u0)
    cw_kernel<<<CDIV(512 * 64 + 512, 256), 256, 0, stream>>>(
        W_user, b_user, F(L0UM+0), F(L0UM+1), F(L0MU+2), F(L0MU+3), wt_c_user, bc_user);
    // movie: cols 0-255 = W_movie@l0um_Wr (xr_m0), 256-511 = W_movie@l0mu_Wl (xl_m0)
    cw_kernel<<<CDIV(512 * 64 + 512, 256), 256, 0, stream>>>(
        W_movie, b_movie, F(L0UM+2), F(L0UM+3), F(L0MU+0), F(L0MU+1), wt_c_movie, bc_movie);

    // ---- CSR build (both directions) ----
    fill_i32<<<CDIV(2 * (NM + NU), FB), FB, 0, stream>>>(degcur, 0, (long)2 * (NM + NU));
    hist2_kernel<<<CDIV(2 * E, FB), FB, 0, stream>>>(ei_um + E, ei_mu + E, deg_m, deg_u, E);
    const int nbm = CDIV(NM, SCAN_T * SCAN_E), nbu = CDIV(NU, SCAN_T * SCAN_E);
    scan1_dual_kernel<<<dim3(max(nbm, nbu), 2), SCAN_T, 0, stream>>>(
        deg_m, off_m, bsum_m, NM, deg_u, off_u, bsum_u, NU);
    scan2_dual_kernel<<<1, 128, 0, stream>>>(bsum_m, nbm, bsum_u, nbu);
    scan3_dual_kernel<<<dim3(CDIV(max(NM, NU), FB), 2), FB, 0, stream>>>(
        off_m, bsum_m, NM, off_u, bsum_u, NU);
    csr_fill2_kernel<<<CDIV(2 * E, FB), FB, 0, stream>>>(
        ei_um, ei_um + E, ea_um, off_m, cur_m, rec_m,
        ei_mu, ei_mu + E, ea_mu, off_u, cur_u, rec_u, E);

    // ---- layer-0 projections (phase-0 folded): gather f32 emb, K=64, N=512 ----
    gemm_split_kernel<64, 512, true><<<CDIV(NU, 64), 256, 0, stream>>>(
        user_emb, user_ids, wt_c_user, bc_user, bc_user + 256,
        (unsigned short*)UB1, (unsigned short*)UB2, NU);          // xl_u0, xr_u0
    gemm_split_kernel<64, 512, true><<<CDIV(NM, 64), 256, 0, stream>>>(
        movie_emb, movie_ids, wt_c_movie, bc_movie, bc_movie + 256,
        (unsigned short*)MB1, (unsigned short*)MB3, NM);          // xr_m0, xl_m0

    // ---- layer 0 fused GAT ----
    gat_fused_kernel<true><<<CDIV(NM, 4), 256, 0, stream>>>(
        deg_m, off_m, rec_m, UB1, MB1, F(L0UM+4), F(L0UM+5), F(L0UM+6), g0m, be0m, MB2, NM);  // xm1
    gat_fused_kernel<true><<<CDIV(NU, 4), 256, 0, stream>>>(
        deg_u, off_u, rec_u, MB3, UB2, F(L0MU+4), F(L0MU+5), F(L0MU+6), g0u, be0u, UB1, NU);  // xu1

    // ---- layer-1 projections: one N=512 GEMM per node type ----
    gemm_split_kernel<256, 512, false><<<CDIV(NU, 64), 256, 0, stream>>>(
        (unsigned short*)UB1, nullptr, wt_l1um_l, F(L1UM+1), F(L1MU+3),
        (unsigned short*)UB2, (unsigned short*)UB3, NU);          // xl_u1, xr_u1
    gemm_split_kernel<256, 512, false><<<CDIV(NM, 64), 256, 0, stream>>>(
        (unsigned short*)MB2, nullptr, wt_l1um_r, F(L1UM+3), F(L1MU+1),
        (unsigned short*)MB1, (unsigned short*)MB3, NM);          // xr_m1, xl_m1

    // ---- layer 1 fused GAT ----
    gat_fused_kernel<false><<<CDIV(NM, 4), 256, 0, stream>>>(
        deg_m, off_m, rec_m, UB2, MB1, F(L1UM+4), F(L1UM+5), F(L1UM+6), g1m, be1m, out_m, NM);
    gat_fused_kernel<false><<<CDIV(NU, 4), 256, 0, stream>>>(
        deg_u, off_u, rec_u, MB3, UB3, F(L1MU+4), F(L1MU+5), F(L1MU+6), g1u, be1u, out_u, NU);
}

// Round 8
// 508.572 us; speedup vs baseline: 1.3915x; 1.3915x over previous
//
#include <hip/hip_runtime.h>
#include <hip/hip_bf16.h>
#include <cstdint>

typedef __hip_bfloat16 bf16;
#define CDIV(a,b) (((a)+(b)-1)/(b))

typedef __attribute__((ext_vector_type(8))) short short8;
typedef __attribute__((ext_vector_type(8))) unsigned short usht8;
typedef __attribute__((ext_vector_type(4))) float f32x4v;

struct us4 { unsigned short x, y, z, w; };

// ---------------- device helpers ----------------
__device__ __forceinline__ float lrelu02(float x) { return fmaxf(x, 0.f) + 0.2f * fminf(x, 0.f); }

__device__ __forceinline__ float b2f(unsigned short u) {
    return __uint_as_float((unsigned)u << 16);
}
// f32 -> bf16 bits, round-to-nearest-even
__device__ __forceinline__ unsigned short f2b(float f) {
    unsigned u = __float_as_uint(f);
    unsigned r = u + 0x7FFFu + ((u >> 16) & 1u);
    return (unsigned short)(r >> 16);
}

// swizzled LDS index (ushort units) for [row][32] tiles, 8-elem granularity
__device__ __forceinline__ int swz(int row, int kg) {
    return row * 32 + (kg ^ ((row >> 1) & 3)) * 8;
}

// ---------------- fill ----------------
__global__ void fill_i32(int* __restrict__ p, int v, long n) {
    long i = (long)blockIdx.x * blockDim.x + threadIdx.x;
    long st = (long)gridDim.x * blockDim.x;
    for (; i < n; i += st) p[i] = v;
}

// ---------------- CSR build (both directions fused) ----------------
__global__ void hist2_kernel(const int* __restrict__ edm, const int* __restrict__ edu,
                             int* __restrict__ deg_m, int* __restrict__ deg_u, int E) {
    int e = blockIdx.x * blockDim.x + threadIdx.x;
    if (e < E) atomicAdd(&deg_m[edm[e]], 1);
    else if (e < 2 * E) atomicAdd(&deg_u[edu[e - E]], 1);
}

#define SCAN_T 256
#define SCAN_E 16
__global__ void __launch_bounds__(SCAN_T) scan1_dual_kernel(
    const int* __restrict__ deg0, int* __restrict__ off0, int* __restrict__ bsum0, int n0,
    const int* __restrict__ deg1, int* __restrict__ off1, int* __restrict__ bsum1, int n1)
{
    const int* deg = blockIdx.y ? deg1 : deg0;
    int* off  = blockIdx.y ? off1 : off0;
    int* bsum = blockIdx.y ? bsum1 : bsum0;
    const int n = blockIdx.y ? n1 : n0;

    __shared__ int lds[SCAN_T];
    const int tb = blockIdx.x * (SCAN_T * SCAN_E) + threadIdx.x * SCAN_E;
    int v[SCAN_E];
    int tot = 0;
#pragma unroll
    for (int j = 0; j < SCAN_E; ++j) {
        v[j] = (tb + j < n) ? deg[tb + j] : 0;
        tot += v[j];
    }
    lds[threadIdx.x] = tot;
    __syncthreads();
    for (int s = 1; s < SCAN_T; s <<= 1) {
        int t = (threadIdx.x >= s) ? lds[threadIdx.x - s] : 0;
        __syncthreads();
        lds[threadIdx.x] += t;
        __syncthreads();
    }
    int run = (threadIdx.x > 0) ? lds[threadIdx.x - 1] : 0;
#pragma unroll
    for (int j = 0; j < SCAN_E; ++j) {
        if (tb + j < n) off[tb + j] = run;
        run += v[j];
    }
    if (threadIdx.x == SCAN_T - 1) bsum[blockIdx.x] = lds[SCAN_T - 1];
}
__global__ void scan2_dual_kernel(int* __restrict__ bm, int nbm, int* __restrict__ bu, int nbu) {
    int t = threadIdx.x & 63;
    int* b = (threadIdx.x >= 64) ? bu : bm;
    int nb = (threadIdx.x >= 64) ? nbu : nbm;
    int orig = (t < nb) ? b[t] : 0;
    int v = orig;
    for (int s = 1; s < 64; s <<= 1) {
        int u = __shfl_up(v, s);
        if (t >= s) v += u;
    }
    if (t < nb) b[t] = v - orig;
}
__global__ void scan3_dual_kernel(int* __restrict__ off0, const int* __restrict__ bsum0, int n0,
                                  int* __restrict__ off1, const int* __restrict__ bsum1, int n1) {
    int* off = blockIdx.y ? off1 : off0;
    const int* bsum = blockIdx.y ? bsum1 : bsum0;
    const int n = blockIdx.y ? n1 : n0;
    int i = blockIdx.x * blockDim.x + threadIdx.x;
    if (i < n) off[i] += bsum[i / (SCAN_T * SCAN_E)];
}

__global__ void csr_fill2_kernel(
    const int* __restrict__ esm, const int* __restrict__ edm, const float* __restrict__ eam,
    const int* __restrict__ offm, int* __restrict__ curm, int2* __restrict__ recm,
    const int* __restrict__ esu, const int* __restrict__ edu, const float* __restrict__ eau,
    const int* __restrict__ offu, int* __restrict__ curu, int2* __restrict__ recu, int E)
{
    int e = blockIdx.x * blockDim.x + threadIdx.x;
    if (e < E) {
        int d = edm[e];
        int r = atomicAdd(&curm[d], 1);
        int2 q; q.x = esm[e]; q.y = __float_as_int(eam[e]);
        recm[offm[d] + r] = q;
    } else if (e < 2 * E) {
        e -= E;
        int d = edu[e];
        int r = atomicAdd(&curu[d], 1);
        int2 q; q.x = esu[e]; q.y = __float_as_int(eau[e]);
        recu[offu[d] + r] = q;
    }
}

// ---------------- weight transpose+convert: W[K][N] f32 -> Wt[N][K] bf16 ----
struct TxArgs {
    const float* src[4];
    unsigned short* dst[4];
};
__global__ void txp_kernel(TxArgs a) {
    const int m = blockIdx.y;
    const int K = 256, N = 256;
    const long total = (long)K * N;
    const float* __restrict__ s = a.src[m];
    unsigned short* __restrict__ d = a.dst[m];
    for (long i = (long)blockIdx.x * blockDim.x + threadIdx.x; i < total;
         i += (long)gridDim.x * blockDim.x) {
        int k = (int)(i >> 8), nn = (int)(i & 255);
        d[(long)nn * K + k] = f2b(s[i]);
    }
}

// ---------------- combine phase-0 + layer-0 weights (all affine) ----------
__global__ void cw_kernel(const float* __restrict__ Wu, const float* __restrict__ bu,
                          const float* __restrict__ Wa, const float* __restrict__ ba,
                          const float* __restrict__ Wb, const float* __restrict__ bb,
                          unsigned short* __restrict__ wt, float* __restrict__ bc)
{
    int tid = blockIdx.x * blockDim.x + threadIdx.x;
    if (tid < 512 * 64) {
        int nn = tid >> 6, k = tid & 63;
        const float* Ws = (nn < 256) ? Wa : Wb;
        int nc = nn & 255;
        float s = 0.f;
        for (int c = 0; c < 64; ++c) s = fmaf(Wu[k * 64 + c], Ws[c * 256 + nc], s);
        wt[nn * 64 + k] = f2b(s);
    } else if (tid < 512 * 64 + 512) {
        int nn = tid - 512 * 64;
        const float* Ws = (nn < 256) ? Wa : Wb;
        const float* bs = (nn < 256) ? ba : bb;
        int nc = nn & 255;
        float s = bs[nc];
        for (int c = 0; c < 64; ++c) s = fmaf(bu[c], Ws[c * 256 + nc], s);
        bc[nn] = s;
    }
}

// ---------------- MFMA GEMM, paired column-halves ----------------
// bid&1 selects {Wt, bias, Y} half; bid>>1 is the 64-row block. Adjacent
// even/odd blocks share the A-tile -> L2 reuse. Per-block: 64x256 tile,
// acc[4][4] (64 VGPR), 20KB LDS — the proven R5 geometry.
template<int K, bool GATHER>
__global__ void __launch_bounds__(256) gemm256_kernel(
    const void* __restrict__ Asrc, const int* __restrict__ ids,
    const unsigned short* __restrict__ Wt0, const unsigned short* __restrict__ Wt1,
    const float* __restrict__ bias0, const float* __restrict__ bias1,
    unsigned short* __restrict__ Y0, unsigned short* __restrict__ Y1, int n)
{
    const int t = threadIdx.x;
    const int wid = t >> 6, lane = t & 63;
    const int half = blockIdx.x & 1;
    const int row0 = (blockIdx.x >> 1) * 64;
    const unsigned short* __restrict__ Wt = half ? Wt1 : Wt0;
    const float* __restrict__ bias = half ? bias1 : bias0;
    unsigned short* __restrict__ Y = half ? Y1 : Y0;

    __shared__ unsigned short As[64 * 32];
    __shared__ unsigned short Ws[256 * 32];

    f32x4v acc[4][4];
#pragma unroll
    for (int rt = 0; rt < 4; ++rt)
#pragma unroll
        for (int ct = 0; ct < 4; ++ct) acc[rt][ct] = (f32x4v){0.f, 0.f, 0.f, 0.f};

    const int r_st = t >> 2, kg_st = t & 3;
    const int grow = row0 + r_st;
    long abase = 0;
    if (grow < n) abase = GATHER ? (long)ids[grow] * K : (long)grow * K;

    for (int kt = 0; kt < K / 32; ++kt) {
        usht8 av = (usht8)0;
        if (grow < n) {
            if (GATHER) {
                const float* p = (const float*)Asrc + abase + kt * 32 + kg_st * 8;
#pragma unroll
                for (int j = 0; j < 8; ++j) av[j] = f2b(p[j]);
            } else {
                av = *(const usht8*)((const unsigned short*)Asrc + abase + kt * 32 + kg_st * 8);
            }
        }
        *(usht8*)&As[swz(r_st, kg_st)] = av;
#pragma unroll
        for (int i = 0; i < 4; ++i) {
            int idx = t + i * 256;
            int c = idx >> 2, kg = idx & 3;
            *(usht8*)&Ws[swz(c, kg)] = *(const usht8*)&Wt[(long)c * K + kt * 32 + kg * 8];
        }
        __syncthreads();

        const int kgrp = lane >> 4;
        short8 af[4];
#pragma unroll
        for (int rt = 0; rt < 4; ++rt)
            af[rt] = *(const short8*)&As[swz(rt * 16 + (lane & 15), kgrp)];
#pragma unroll
        for (int ct = 0; ct < 4; ++ct) {
            int col = wid * 64 + ct * 16 + (lane & 15);
            short8 bfr = *(const short8*)&Ws[swz(col, kgrp)];
#pragma unroll
            for (int rt = 0; rt < 4; ++rt)
                acc[rt][ct] = __builtin_amdgcn_mfma_f32_16x16x32_bf16(af[rt], bfr, acc[rt][ct], 0, 0, 0);
        }
        __syncthreads();
    }

#pragma unroll
    for (int ct = 0; ct < 4; ++ct) {
        int col = wid * 64 + ct * 16 + (lane & 15);
        float bb = bias[col];
#pragma unroll
        for (int rt = 0; rt < 4; ++rt) {
#pragma unroll
            for (int j = 0; j < 4; ++j) {
                int row = row0 + rt * 16 + (lane >> 4) * 4 + j;
                if (row < n) Y[(long)row * 256 + col] = f2b(acc[rt][ct][j] + bb);
            }
        }
    }
}

// ---------------- fused GATv2 layer (head-split lanes) ------
// lane = h*16 + q; lane owns channels c = h*64 + q*4 .. +3
// one wave per destination; 4-edge batches for load ILP; branchless online
// softmax; record broadcasts via v_readlane (uniform index -> SGPR)
template<bool CONCAT>
__global__ void __launch_bounds__(256) gat_fused_kernel(
    const int* __restrict__ deg, const int* __restrict__ off,
    const int2* __restrict__ rec,
    const bf16* __restrict__ xl, const bf16* __restrict__ xr,
    const float* __restrict__ We, const float* __restrict__ att,
    const float* __restrict__ bias,
    const float* __restrict__ g, const float* __restrict__ be,
    void* __restrict__ yout, int n)
{
    const int lane = threadIdx.x & 63;
    const int d = blockIdx.x * 4 + (threadIdx.x >> 6);
    if (d >= n) return;
    const int q = lane & 15;
    const int c0 = ((lane >> 4) << 6) + (q << 2);   // h*64 + q*4

    float4 We4 = *(const float4*)(We + c0);
    float4 att4 = *(const float4*)(att + c0);
    us4 xrv = *(const us4*)((const unsigned short*)xr + (long)d * 256 + c0);
    float xr4[4] = {b2f(xrv.x), b2f(xrv.y), b2f(xrv.z), b2f(xrv.w)};

    float m = -1e30f, den = 0.f;
    float acc[4] = {0.f, 0.f, 0.f, 0.f};

    const int dg = deg[d], o0 = off[d];
    const unsigned short* __restrict__ xlp = (const unsigned short*)xl;

    for (int base = 0; base < dg; base += 64) {
        int2 r;
        if (base + lane < dg) r = rec[o0 + base + lane];
        else { r.x = 0; r.y = 0; }
        const int cnt = min(dg - base, 64);
        for (int j = 0; j < cnt; j += 4) {
            int sA[4], aB[4];
            us4 xvA[4];
#pragma unroll
            for (int u = 0; u < 4; ++u) {
                sA[u] = __builtin_amdgcn_readlane(r.x, j + u);   // SGPR broadcast
                aB[u] = __builtin_amdgcn_readlane(r.y, j + u);
            }
#pragma unroll
            for (int u = 0; u < 4; ++u)
                xvA[u] = *(const us4*)(xlp + (long)sA[u] * 256 + c0);
#pragma unroll
            for (int u = 0; u < 4; ++u) {
                const float a = __int_as_float(aB[u]);
                float xv[4] = {b2f(xvA[u].x), b2f(xvA[u].y), b2f(xvA[u].z), b2f(xvA[u].w)};
                float part = 0.f;
#pragma unroll
                for (int i = 0; i < 4; ++i) {
                    float t = xv[i] + fmaf(a, (&We4.x)[i], xr4[i]);
                    part = fmaf(lrelu02(t), (&att4.x)[i], part);
                }
                // reduce over the 16-lane head group (all 4 heads in parallel)
#pragma unroll
                for (int st = 1; st < 16; st <<= 1) part += __shfl_xor(part, st);
                float l = (j + u < cnt) ? part : -1e30f;
                float mn = fmaxf(m, l);
                float sc = __expf(m - mn);
                float p  = __expf(l - mn);
                m = mn;
                den = fmaf(den, sc, p);
#pragma unroll
                for (int i = 0; i < 4; ++i) acc[i] = fmaf(acc[i], sc, p * xv[i]);
            }
        }
    }

    const float id = 1.f / (den + 1e-16f);
    if (CONCAT) {
        float4 bi = *(const float4*)(bias + c0);
        float v[4], s1 = 0.f, s2 = 0.f;
#pragma unroll
        for (int i = 0; i < 4; ++i) {
            v[i] = fmaf(acc[i], id, (&bi.x)[i]);
            s1 += v[i]; s2 = fmaf(v[i], v[i], s2);
        }
#pragma unroll
        for (int st = 1; st < 64; st <<= 1) {
            s1 += __shfl_xor(s1, st);
            s2 += __shfl_xor(s2, st);
        }
        float mean = s1 * (1.f / 256.f);
        float var = s2 * (1.f / 256.f) - mean * mean;
        float rr = rsqrtf(var + 1e-5f);
        float4 gg = *(const float4*)(g + c0);
        float4 bb = *(const float4*)(be + c0);
        us4 o;
        o.x = f2b(lrelu02(fmaf((&gg.x)[0] * rr, v[0] - mean, (&bb.x)[0])));
        o.y = f2b(lrelu02(fmaf((&gg.x)[1] * rr, v[1] - mean, (&bb.x)[1])));
        o.z = f2b(lrelu02(fmaf((&gg.x)[2] * rr, v[2] - mean, (&bb.x)[2])));
        o.w = f2b(lrelu02(fmaf((&gg.x)[3] * rr, v[3] - mean, (&bb.x)[3])));
        *(us4*)((unsigned short*)yout + (long)d * 256 + c0) = o;
    } else {
        float vh[4];
#pragma unroll
        for (int i = 0; i < 4; ++i) vh[i] = acc[i] * id;
        // sum over the 4 head groups (lanes differing in bits 4,5)
#pragma unroll
        for (int st = 16; st < 64; st <<= 1)
#pragma unroll
            for (int i = 0; i < 4; ++i) vh[i] += __shfl_xor(vh[i], st);
        const int oc = q << 2;
        float4 bi = *(const float4*)(bias + oc);
        float v[4], s1 = 0.f, s2 = 0.f;
#pragma unroll
        for (int i = 0; i < 4; ++i) {
            v[i] = fmaf(0.25f, vh[i], (&bi.x)[i]);
            s1 += v[i]; s2 = fmaf(v[i], v[i], s2);
        }
#pragma unroll
        for (int st = 1; st < 16; st <<= 1) {
            s1 += __shfl_xor(s1, st);
            s2 += __shfl_xor(s2, st);
        }
        float mean = s1 * (1.f / 64.f);
        float var = s2 * (1.f / 64.f) - mean * mean;
        float rr = rsqrtf(var + 1e-5f);
        float4 gg = *(const float4*)(g + oc);
        float4 bb = *(const float4*)(be + oc);
        if (lane < 16) {
            float4 o;
            o.x = lrelu02(fmaf((&gg.x)[0] * rr, v[0] - mean, (&bb.x)[0]));
            o.y = lrelu02(fmaf((&gg.x)[1] * rr, v[1] - mean, (&bb.x)[1]));
            o.z = lrelu02(fmaf((&gg.x)[2] * rr, v[2] - mean, (&bb.x)[2]));
            o.w = lrelu02(fmaf((&gg.x)[3] * rr, v[3] - mean, (&bb.x)[3]));
            *(float4*)((float*)yout + (long)d * 64 + oc) = o;
        }
    }
}

// ---------------- host orchestration ----------------
extern "C" void kernel_launch(void* const* d_in, const int* in_sizes, int n_in,
                              void* d_out, int out_size, void* d_ws, size_t ws_size,
                              hipStream_t stream)
{
    auto F = [&](int i) { return (const float*)d_in[i]; };
    auto I = [&](int i) { return (const int*)d_in[i]; };

    const int NU = in_sizes[0];
    const int NM = in_sizes[1];
    const int E  = in_sizes[2] / 2;

    const int* user_ids  = I(0);
    const int* movie_ids = I(1);
    const int* ei_um = I(2);
    const int* ei_mu = I(3);
    const float* ea_um = F(4);
    const float* ea_mu = F(5);
    const float* user_emb  = F(6);
    const float* movie_emb = F(7);
    const float* W_user = F(8),  *b_user = F(9);
    const float* W_movie = F(10), *b_movie = F(11);
    const int L0UM = 12, L0MU = 19, L1UM = 26, L1MU = 33;
    const float* g0u = F(40), *be0u = F(41);
    const float* g0m = F(42), *be0m = F(43);
    const float* g1u = F(44), *be1u = F(45);
    const float* g1m = F(46), *be1m = F(47);

    // ---- workspace layout ----
    char* w = (char*)d_ws;
    size_t off = 0;
    auto alloc = [&](size_t bytes) -> void* {
        void* p = w + off;
        off = (off + bytes + 255) & ~(size_t)255;
        return p;
    };
    bf16* UB1 = (bf16*)alloc((size_t)NU * 256 * 2);
    bf16* UB2 = (bf16*)alloc((size_t)NU * 256 * 2);
    bf16* UB3 = (bf16*)alloc((size_t)NU * 256 * 2);
    bf16* MB1 = (bf16*)alloc((size_t)NM * 256 * 2);
    bf16* MB2 = (bf16*)alloc((size_t)NM * 256 * 2);
    bf16* MB3 = (bf16*)alloc((size_t)NM * 256 * 2);
    int* degcur = (int*)alloc((size_t)2 * (NM + NU) * 4);
    int* deg_m = degcur;
    int* deg_u = degcur + NM;
    int* cur_m = degcur + NM + NU;
    int* cur_u = degcur + 2 * NM + NU;
    int* off_m = (int*)alloc((size_t)NM * 4);
    int* off_u = (int*)alloc((size_t)NU * 4);
    int2* rec_m = (int2*)alloc((size_t)(E + 4) * 8);
    int2* rec_u = (int2*)alloc((size_t)(E + 4) * 8);
    int* bsum_m = (int*)alloc(64 * 4);
    int* bsum_u = (int*)alloc(64 * 4);
    unsigned short* wt_l1um_l = (unsigned short*)alloc(256 * 256 * 2);
    unsigned short* wt_l1mu_r = (unsigned short*)alloc(256 * 256 * 2);
    unsigned short* wt_l1um_r = (unsigned short*)alloc(256 * 256 * 2);
    unsigned short* wt_l1mu_l = (unsigned short*)alloc(256 * 256 * 2);
    unsigned short* wt_c_user  = (unsigned short*)alloc(512 * 64 * 2);
    unsigned short* wt_c_movie = (unsigned short*)alloc(512 * 64 * 2);
    float* bc_user  = (float*)alloc(512 * 4);
    float* bc_movie = (float*)alloc(512 * 4);
    if (off > ws_size) return;

    float* out_u = (float*)d_out;
    float* out_m = out_u + (size_t)NU * 64;

    const int FB = 256;

    // ---- weight prep ----
    TxArgs tx;
    tx.src[0] = F(L1UM+0); tx.dst[0] = wt_l1um_l;
    tx.src[1] = F(L1MU+2); tx.dst[1] = wt_l1mu_r;
    tx.src[2] = F(L1UM+2); tx.dst[2] = wt_l1um_r;
    tx.src[3] = F(L1MU+0); tx.dst[3] = wt_l1mu_l;
    txp_kernel<<<dim3(64, 4), 256, 0, stream>>>(tx);
    // user: cols 0-255 = W_user@l0um_Wl (xl_u0), 256-511 = W_user@l0mu_Wr (xr_u0)
    cw_kernel<<<CDIV(512 * 64 + 512, 256), 256, 0, stream>>>(
        W_user, b_user, F(L0UM+0), F(L0UM+1), F(L0MU+2), F(L0MU+3), wt_c_user, bc_user);
    // movie: cols 0-255 = W_movie@l0um_Wr (xr_m0), 256-511 = W_movie@l0mu_Wl (xl_m0)
    cw_kernel<<<CDIV(512 * 64 + 512, 256), 256, 0, stream>>>(
        W_movie, b_movie, F(L0UM+2), F(L0UM+3), F(L0MU+0), F(L0MU+1), wt_c_movie, bc_movie);

    // ---- CSR build (both directions) ----
    fill_i32<<<CDIV(2 * (NM + NU), FB), FB, 0, stream>>>(degcur, 0, (long)2 * (NM + NU));
    hist2_kernel<<<CDIV(2 * E, FB), FB, 0, stream>>>(ei_um + E, ei_mu + E, deg_m, deg_u, E);
    const int nbm = CDIV(NM, SCAN_T * SCAN_E), nbu = CDIV(NU, SCAN_T * SCAN_E);
    scan1_dual_kernel<<<dim3(max(nbm, nbu), 2), SCAN_T, 0, stream>>>(
        deg_m, off_m, bsum_m, NM, deg_u, off_u, bsum_u, NU);
    scan2_dual_kernel<<<1, 128, 0, stream>>>(bsum_m, nbm, bsum_u, nbu);
    scan3_dual_kernel<<<dim3(CDIV(max(NM, NU), FB), 2), FB, 0, stream>>>(
        off_m, bsum_m, NM, off_u, bsum_u, NU);
    csr_fill2_kernel<<<CDIV(2 * E, FB), FB, 0, stream>>>(
        ei_um, ei_um + E, ea_um, off_m, cur_m, rec_m,
        ei_mu, ei_mu + E, ea_mu, off_u, cur_u, rec_u, E);

    // ---- layer-0 projections (phase-0 folded): gather f32 emb, K=64 ----
    gemm256_kernel<64, true><<<CDIV(NU, 64) * 2, 256, 0, stream>>>(
        user_emb, user_ids, wt_c_user, wt_c_user + 256 * 64, bc_user, bc_user + 256,
        (unsigned short*)UB1, (unsigned short*)UB2, NU);          // xl_u0, xr_u0
    gemm256_kernel<64, true><<<CDIV(NM, 64) * 2, 256, 0, stream>>>(
        movie_emb, movie_ids, wt_c_movie, wt_c_movie + 256 * 64, bc_movie, bc_movie + 256,
        (unsigned short*)MB1, (unsigned short*)MB3, NM);          // xr_m0, xl_m0

    // ---- layer 0 fused GAT ----
    gat_fused_kernel<true><<<CDIV(NM, 4), 256, 0, stream>>>(
        deg_m, off_m, rec_m, UB1, MB1, F(L0UM+4), F(L0UM+5), F(L0UM+6), g0m, be0m, MB2, NM);  // xm1
    gat_fused_kernel<true><<<CDIV(NU, 4), 256, 0, stream>>>(
        deg_u, off_u, rec_u, MB3, UB2, F(L0MU+4), F(L0MU+5), F(L0MU+6), g0u, be0u, UB1, NU);  // xu1

    // ---- layer-1 projections ----
    gemm256_kernel<256, false><<<CDIV(NU, 64) * 2, 256, 0, stream>>>(
        (unsigned short*)UB1, nullptr, wt_l1um_l, wt_l1mu_r, F(L1UM+1), F(L1MU+3),
        (unsigned short*)UB2, (unsigned short*)UB3, NU);          // xl_u1, xr_u1
    gemm256_kernel<256, false><<<CDIV(NM, 64) * 2, 256, 0, stream>>>(
        (unsigned short*)MB2, nullptr, wt_l1um_r, wt_l1mu_l, F(L1UM+3), F(L1MU+1),
        (unsigned short*)MB1, (unsigned short*)MB3, NM);          // xr_m1, xl_m1

    // ---- layer 1 fused GAT ----
    gat_fused_kernel<false><<<CDIV(NM, 4), 256, 0, stream>>>(
        deg_m, off_m, rec_m, UB2, MB1, F(L1UM+4), F(L1UM+5), F(L1UM+6), g1m, be1m, out_m, NM);
    gat_fused_kernel<false><<<CDIV(NU, 4), 256, 0, stream>>>(
        deg_u, off_u, rec_u, MB3, UB3, F(L1MU+4), F(L1MU+5), F(L1MU+6), g1u, be1u, out_u, NU);
}

// Round 9
// 417.033 us; speedup vs baseline: 1.6970x; 1.2195x over previous
//
#include <hip/hip_runtime.h>
#include <hip/hip_bf16.h>
#include <cstdint>

typedef __hip_bfloat16 bf16;
#define CDIV(a,b) (((a)+(b)-1)/(b))

typedef __attribute__((ext_vector_type(8))) short short8;
typedef __attribute__((ext_vector_type(8))) unsigned short usht8;
typedef __attribute__((ext_vector_type(4))) float f32x4v;

struct us4 { unsigned short x, y, z, w; };

// ---------------- device helpers ----------------
__device__ __forceinline__ float lrelu02(float x) { return fmaxf(x, 0.f) + 0.2f * fminf(x, 0.f); }

__device__ __forceinline__ float b2f(unsigned short u) {
    return __uint_as_float((unsigned)u << 16);
}
// f32 -> bf16 bits, round-to-nearest-even
__device__ __forceinline__ unsigned short f2b(float f) {
    unsigned u = __float_as_uint(f);
    unsigned r = u + 0x7FFFu + ((u >> 16) & 1u);
    return (unsigned short)(r >> 16);
}

// swizzled LDS index (ushort units) for [row][32] tiles, 8-elem granularity
__device__ __forceinline__ int swz(int row, int kg) {
    return row * 32 + (kg ^ ((row >> 1) & 3)) * 8;
}

// ---------------- fill ----------------
__global__ void fill_i32(int* __restrict__ p, int v, long n) {
    long i = (long)blockIdx.x * blockDim.x + threadIdx.x;
    long st = (long)gridDim.x * blockDim.x;
    for (; i < n; i += st) p[i] = v;
}

// ---------------- CSR build (both directions fused) ----------------
__global__ void hist2_kernel(const int* __restrict__ edm, const int* __restrict__ edu,
                             int* __restrict__ deg_m, int* __restrict__ deg_u, int E) {
    int e = blockIdx.x * blockDim.x + threadIdx.x;
    if (e < E) atomicAdd(&deg_m[edm[e]], 1);
    else if (e < 2 * E) atomicAdd(&deg_u[edu[e - E]], 1);
}

#define SCAN_T 256
#define SCAN_E 16
__global__ void __launch_bounds__(SCAN_T) scan1_dual_kernel(
    const int* __restrict__ deg0, int* __restrict__ off0, int* __restrict__ bsum0, int n0,
    const int* __restrict__ deg1, int* __restrict__ off1, int* __restrict__ bsum1, int n1)
{
    const int* deg = blockIdx.y ? deg1 : deg0;
    int* off  = blockIdx.y ? off1 : off0;
    int* bsum = blockIdx.y ? bsum1 : bsum0;
    const int n = blockIdx.y ? n1 : n0;

    __shared__ int lds[SCAN_T];
    const int tb = blockIdx.x * (SCAN_T * SCAN_E) + threadIdx.x * SCAN_E;
    int v[SCAN_E];
    int tot = 0;
#pragma unroll
    for (int j = 0; j < SCAN_E; ++j) {
        v[j] = (tb + j < n) ? deg[tb + j] : 0;
        tot += v[j];
    }
    lds[threadIdx.x] = tot;
    __syncthreads();
    for (int s = 1; s < SCAN_T; s <<= 1) {
        int t = (threadIdx.x >= s) ? lds[threadIdx.x - s] : 0;
        __syncthreads();
        lds[threadIdx.x] += t;
        __syncthreads();
    }
    int run = (threadIdx.x > 0) ? lds[threadIdx.x - 1] : 0;
#pragma unroll
    for (int j = 0; j < SCAN_E; ++j) {
        if (tb + j < n) off[tb + j] = run;
        run += v[j];
    }
    if (threadIdx.x == SCAN_T - 1) bsum[blockIdx.x] = lds[SCAN_T - 1];
}
__global__ void scan2_dual_kernel(int* __restrict__ bm, int nbm, int* __restrict__ bu, int nbu) {
    int t = threadIdx.x & 63;
    int* b = (threadIdx.x >= 64) ? bu : bm;
    int nb = (threadIdx.x >= 64) ? nbu : nbm;
    int orig = (t < nb) ? b[t] : 0;
    int v = orig;
    for (int s = 1; s < 64; s <<= 1) {
        int u = __shfl_up(v, s);
        if (t >= s) v += u;
    }
    if (t < nb) b[t] = v - orig;
}
__global__ void scan3_dual_kernel(int* __restrict__ off0, const int* __restrict__ bsum0, int n0,
                                  int* __restrict__ off1, const int* __restrict__ bsum1, int n1) {
    int* off = blockIdx.y ? off1 : off0;
    const int* bsum = blockIdx.y ? bsum1 : bsum0;
    const int n = blockIdx.y ? n1 : n0;
    int i = blockIdx.x * blockDim.x + threadIdx.x;
    if (i < n) off[i] += bsum[i / (SCAN_T * SCAN_E)];
}

__global__ void csr_fill2_kernel(
    const int* __restrict__ esm, const int* __restrict__ edm, const float* __restrict__ eam,
    const int* __restrict__ offm, int* __restrict__ curm, int2* __restrict__ recm,
    const int* __restrict__ esu, const int* __restrict__ edu, const float* __restrict__ eau,
    const int* __restrict__ offu, int* __restrict__ curu, int2* __restrict__ recu, int E)
{
    int e = blockIdx.x * blockDim.x + threadIdx.x;
    if (e < E) {
        int d = edm[e];
        int r = atomicAdd(&curm[d], 1);
        int2 q; q.x = esm[e]; q.y = __float_as_int(eam[e]);
        recm[offm[d] + r] = q;
    } else if (e < 2 * E) {
        e -= E;
        int d = edu[e];
        int r = atomicAdd(&curu[d], 1);
        int2 q; q.x = esu[e]; q.y = __float_as_int(eau[e]);
        recu[offu[d] + r] = q;
    }
}

// ---------------- weight transpose+convert: W[K][N] f32 -> Wt[N][K] bf16 ----
struct TxArgs {
    const float* src[4];
    unsigned short* dst[4];
};
__global__ void txp_kernel(TxArgs a) {
    const int m = blockIdx.y;
    const int K = 256, N = 256;
    const long total = (long)K * N;
    const float* __restrict__ s = a.src[m];
    unsigned short* __restrict__ d = a.dst[m];
    for (long i = (long)blockIdx.x * blockDim.x + threadIdx.x; i < total;
         i += (long)gridDim.x * blockDim.x) {
        int k = (int)(i >> 8), nn = (int)(i & 255);
        d[(long)nn * K + k] = f2b(s[i]);
    }
}

// ---------------- combine phase-0 + layer-0 weights (all affine) ----------
__global__ void cw_kernel(const float* __restrict__ Wu, const float* __restrict__ bu,
                          const float* __restrict__ Wa, const float* __restrict__ ba,
                          const float* __restrict__ Wb, const float* __restrict__ bb,
                          unsigned short* __restrict__ wt, float* __restrict__ bc)
{
    int tid = blockIdx.x * blockDim.x + threadIdx.x;
    if (tid < 512 * 64) {
        int nn = tid >> 6, k = tid & 63;
        const float* Ws = (nn < 256) ? Wa : Wb;
        int nc = nn & 255;
        float s = 0.f;
        for (int c = 0; c < 64; ++c) s = fmaf(Wu[k * 64 + c], Ws[c * 256 + nc], s);
        wt[nn * 64 + k] = f2b(s);
    } else if (tid < 512 * 64 + 512) {
        int nn = tid - 512 * 64;
        const float* Ws = (nn < 256) ? Wa : Wb;
        const float* bs = (nn < 256) ? ba : bb;
        int nc = nn & 255;
        float s = bs[nc];
        for (int c = 0; c < 64; ++c) s = fmaf(bu[c], Ws[c * 256 + nc], s);
        bc[nn] = s;
    }
}

// ---------------- MFMA GEMM, paired column-halves, LDS-staged epilogue ----
// bid&1 selects {Wt, bias, Y} half; bid>>1 is the 64-row block. Adjacent
// even/odd blocks share the A-tile -> L2 reuse. 64x256 tile, acc[4][4],
// 20KB LDS. Epilogue stages C through LDS -> dense 16B/lane stores.
template<int K, bool GATHER>
__global__ void __launch_bounds__(256) gemm256_kernel(
    const void* __restrict__ Asrc, const int* __restrict__ ids,
    const unsigned short* __restrict__ Wt0, const unsigned short* __restrict__ Wt1,
    const float* __restrict__ bias0, const float* __restrict__ bias1,
    unsigned short* __restrict__ Y0, unsigned short* __restrict__ Y1, int n)
{
    const int t = threadIdx.x;
    const int wid = t >> 6, lane = t & 63;
    const int half = blockIdx.x & 1;
    const int row0 = (blockIdx.x >> 1) * 64;
    const unsigned short* __restrict__ Wt = half ? Wt1 : Wt0;
    const float* __restrict__ bias = half ? bias1 : bias0;
    unsigned short* __restrict__ Y = half ? Y1 : Y0;

    __shared__ unsigned short SMEM[64 * 32 + 256 * 32];   // As | Ws; reused as C-stage
    unsigned short* As = SMEM;
    unsigned short* Ws = SMEM + 64 * 32;

    f32x4v acc[4][4];
#pragma unroll
    for (int rt = 0; rt < 4; ++rt)
#pragma unroll
        for (int ct = 0; ct < 4; ++ct) acc[rt][ct] = (f32x4v){0.f, 0.f, 0.f, 0.f};

    const int r_st = t >> 2, kg_st = t & 3;
    const int grow = row0 + r_st;
    long abase = 0;
    if (grow < n) abase = GATHER ? (long)ids[grow] * K : (long)grow * K;

    for (int kt = 0; kt < K / 32; ++kt) {
        usht8 av = (usht8)0;
        if (grow < n) {
            if (GATHER) {
                const float* p = (const float*)Asrc + abase + kt * 32 + kg_st * 8;
#pragma unroll
                for (int j = 0; j < 8; ++j) av[j] = f2b(p[j]);
            } else {
                av = *(const usht8*)((const unsigned short*)Asrc + abase + kt * 32 + kg_st * 8);
            }
        }
        *(usht8*)&As[swz(r_st, kg_st)] = av;
#pragma unroll
        for (int i = 0; i < 4; ++i) {
            int idx = t + i * 256;
            int c = idx >> 2, kg = idx & 3;
            *(usht8*)&Ws[swz(c, kg)] = *(const usht8*)&Wt[(long)c * K + kt * 32 + kg * 8];
        }
        __syncthreads();

        const int kgrp = lane >> 4;
        short8 af[4];
#pragma unroll
        for (int rt = 0; rt < 4; ++rt)
            af[rt] = *(const short8*)&As[swz(rt * 16 + (lane & 15), kgrp)];
#pragma unroll
        for (int ct = 0; ct < 4; ++ct) {
            int col = wid * 64 + ct * 16 + (lane & 15);
            short8 bfr = *(const short8*)&Ws[swz(col, kgrp)];
#pragma unroll
            for (int rt = 0; rt < 4; ++rt)
                acc[rt][ct] = __builtin_amdgcn_mfma_f32_16x16x32_bf16(af[rt], bfr, acc[rt][ct], 0, 0, 0);
        }
        __syncthreads();
    }

    // ---- epilogue: stage bf16 C tile in LDS, store dense 16B chunks ----
    float bb[4];
#pragma unroll
    for (int ct = 0; ct < 4; ++ct) bb[ct] = bias[wid * 64 + ct * 16 + (lane & 15)];

#pragma unroll
    for (int rh = 0; rh < 2; ++rh) {                // rows rh*32 .. rh*32+31
        // stage: lane fragment (row = rt*16 + (lane>>4)*4 + j, col) -> SMEM[32][256]
#pragma unroll
        for (int rt = rh * 2; rt < rh * 2 + 2; ++rt) {
#pragma unroll
            for (int ct = 0; ct < 4; ++ct) {
                int col = wid * 64 + ct * 16 + (lane & 15);
#pragma unroll
                for (int j = 0; j < 4; ++j) {
                    int rl = rt * 16 + (lane >> 4) * 4 + j - rh * 32;
                    SMEM[rl * 256 + col] = f2b(acc[rt][ct][j] + bb[ct]);
                }
            }
        }
        __syncthreads();
        // readout: 1024 chunks of 8 ushorts (16B); 4 per thread, lane-dense
#pragma unroll
        for (int i = 0; i < 4; ++i) {
            int idx = t + i * 256;
            int rl = idx >> 5, cseg = (idx & 31) * 8;
            int row = row0 + rh * 32 + rl;
            if (row < n)
                *(usht8*)&Y[(long)row * 256 + cseg] = *(const usht8*)&SMEM[rl * 256 + cseg];
        }
        __syncthreads();
    }
}

// ---------------- fused GATv2 layer (head-split lanes) ------
// lane = h*16 + q; lane owns channels c = h*64 + q*4 .. +3
// one wave per destination; 4-edge batches for load ILP; branchless online
// softmax; record broadcasts via v_readlane (uniform index -> SGPR)
template<bool CONCAT>
__global__ void __launch_bounds__(256) gat_fused_kernel(
    const int* __restrict__ deg, const int* __restrict__ off,
    const int2* __restrict__ rec,
    const bf16* __restrict__ xl, const bf16* __restrict__ xr,
    const float* __restrict__ We, const float* __restrict__ att,
    const float* __restrict__ bias,
    const float* __restrict__ g, const float* __restrict__ be,
    void* __restrict__ yout, int n)
{
    const int lane = threadIdx.x & 63;
    const int d = blockIdx.x * 4 + (threadIdx.x >> 6);
    if (d >= n) return;
    const int q = lane & 15;
    const int c0 = ((lane >> 4) << 6) + (q << 2);   // h*64 + q*4

    float4 We4 = *(const float4*)(We + c0);
    float4 att4 = *(const float4*)(att + c0);
    us4 xrv = *(const us4*)((const unsigned short*)xr + (long)d * 256 + c0);
    float xr4[4] = {b2f(xrv.x), b2f(xrv.y), b2f(xrv.z), b2f(xrv.w)};

    float m = -1e30f, den = 0.f;
    float acc[4] = {0.f, 0.f, 0.f, 0.f};

    const int dg = deg[d], o0 = off[d];
    const unsigned short* __restrict__ xlp = (const unsigned short*)xl;

    for (int base = 0; base < dg; base += 64) {
        int2 r;
        if (base + lane < dg) r = rec[o0 + base + lane];
        else { r.x = 0; r.y = 0; }
        const int cnt = min(dg - base, 64);
        for (int j = 0; j < cnt; j += 4) {
            int sA[4], aB[4];
            us4 xvA[4];
#pragma unroll
            for (int u = 0; u < 4; ++u) {
                sA[u] = __builtin_amdgcn_readlane(r.x, j + u);   // SGPR broadcast
                aB[u] = __builtin_amdgcn_readlane(r.y, j + u);
            }
#pragma unroll
            for (int u = 0; u < 4; ++u)
                xvA[u] = *(const us4*)(xlp + (long)sA[u] * 256 + c0);
#pragma unroll
            for (int u = 0; u < 4; ++u) {
                const float a = __int_as_float(aB[u]);
                float xv[4] = {b2f(xvA[u].x), b2f(xvA[u].y), b2f(xvA[u].z), b2f(xvA[u].w)};
                float part = 0.f;
#pragma unroll
                for (int i = 0; i < 4; ++i) {
                    float t = xv[i] + fmaf(a, (&We4.x)[i], xr4[i]);
                    part = fmaf(lrelu02(t), (&att4.x)[i], part);
                }
                // reduce over the 16-lane head group (all 4 heads in parallel)
#pragma unroll
                for (int st = 1; st < 16; st <<= 1) part += __shfl_xor(part, st);
                float l = (j + u < cnt) ? part : -1e30f;
                float mn = fmaxf(m, l);
                float sc = __expf(m - mn);
                float p  = __expf(l - mn);
                m = mn;
                den = fmaf(den, sc, p);
#pragma unroll
                for (int i = 0; i < 4; ++i) acc[i] = fmaf(acc[i], sc, p * xv[i]);
            }
        }
    }

    const float id = 1.f / (den + 1e-16f);
    if (CONCAT) {
        float4 bi = *(const float4*)(bias + c0);
        float v[4], s1 = 0.f, s2 = 0.f;
#pragma unroll
        for (int i = 0; i < 4; ++i) {
            v[i] = fmaf(acc[i], id, (&bi.x)[i]);
            s1 += v[i]; s2 = fmaf(v[i], v[i], s2);
        }
#pragma unroll
        for (int st = 1; st < 64; st <<= 1) {
            s1 += __shfl_xor(s1, st);
            s2 += __shfl_xor(s2, st);
        }
        float mean = s1 * (1.f / 256.f);
        float var = s2 * (1.f / 256.f) - mean * mean;
        float rr = rsqrtf(var + 1e-5f);
        float4 gg = *(const float4*)(g + c0);
        float4 bb = *(const float4*)(be + c0);
        us4 o;
        o.x = f2b(lrelu02(fmaf((&gg.x)[0] * rr, v[0] - mean, (&bb.x)[0])));
        o.y = f2b(lrelu02(fmaf((&gg.x)[1] * rr, v[1] - mean, (&bb.x)[1])));
        o.z = f2b(lrelu02(fmaf((&gg.x)[2] * rr, v[2] - mean, (&bb.x)[2])));
        o.w = f2b(lrelu02(fmaf((&gg.x)[3] * rr, v[3] - mean, (&bb.x)[3])));
        *(us4*)((unsigned short*)yout + (long)d * 256 + c0) = o;
    } else {
        float vh[4];
#pragma unroll
        for (int i = 0; i < 4; ++i) vh[i] = acc[i] * id;
        // sum over the 4 head groups (lanes differing in bits 4,5)
#pragma unroll
        for (int st = 16; st < 64; st <<= 1)
#pragma unroll
            for (int i = 0; i < 4; ++i) vh[i] += __shfl_xor(vh[i], st);
        const int oc = q << 2;
        float4 bi = *(const float4*)(bias + oc);
        float v[4], s1 = 0.f, s2 = 0.f;
#pragma unroll
        for (int i = 0; i < 4; ++i) {
            v[i] = fmaf(0.25f, vh[i], (&bi.x)[i]);
            s1 += v[i]; s2 = fmaf(v[i], v[i], s2);
        }
#pragma unroll
        for (int st = 1; st < 16; st <<= 1) {
            s1 += __shfl_xor(s1, st);
            s2 += __shfl_xor(s2, st);
        }
        float mean = s1 * (1.f / 64.f);
        float var = s2 * (1.f / 64.f) - mean * mean;
        float rr = rsqrtf(var + 1e-5f);
        float4 gg = *(const float4*)(g + oc);
        float4 bb = *(const float4*)(be + oc);
        if (lane < 16) {
            float4 o;
            o.x = lrelu02(fmaf((&gg.x)[0] * rr, v[0] - mean, (&bb.x)[0]));
            o.y = lrelu02(fmaf((&gg.x)[1] * rr, v[1] - mean, (&bb.x)[1]));
            o.z = lrelu02(fmaf((&gg.x)[2] * rr, v[2] - mean, (&bb.x)[2]));
            o.w = lrelu02(fmaf((&gg.x)[3] * rr, v[3] - mean, (&bb.x)[3]));
            *(float4*)((float*)yout + (long)d * 64 + oc) = o;
        }
    }
}

// ---------------- host orchestration ----------------
extern "C" void kernel_launch(void* const* d_in, const int* in_sizes, int n_in,
                              void* d_out, int out_size, void* d_ws, size_t ws_size,
                              hipStream_t stream)
{
    auto F = [&](int i) { return (const float*)d_in[i]; };
    auto I = [&](int i) { return (const int*)d_in[i]; };

    const int NU = in_sizes[0];
    const int NM = in_sizes[1];
    const int E  = in_sizes[2] / 2;

    const int* user_ids  = I(0);
    const int* movie_ids = I(1);
    const int* ei_um = I(2);
    const int* ei_mu = I(3);
    const float* ea_um = F(4);
    const float* ea_mu = F(5);
    const float* user_emb  = F(6);
    const float* movie_emb = F(7);
    const float* W_user = F(8),  *b_user = F(9);
    const float* W_movie = F(10), *b_movie = F(11);
    const int L0UM = 12, L0MU = 19, L1UM = 26, L1MU = 33;
    const float* g0u = F(40), *be0u = F(41);
    const float* g0m = F(42), *be0m = F(43);
    const float* g1u = F(44), *be1u = F(45);
    const float* g1m = F(46), *be1m = F(47);

    // ---- workspace layout ----
    char* w = (char*)d_ws;
    size_t off = 0;
    auto alloc = [&](size_t bytes) -> void* {
        void* p = w + off;
        off = (off + bytes + 255) & ~(size_t)255;
        return p;
    };
    bf16* UB1 = (bf16*)alloc((size_t)NU * 256 * 2);
    bf16* UB2 = (bf16*)alloc((size_t)NU * 256 * 2);
    bf16* UB3 = (bf16*)alloc((size_t)NU * 256 * 2);
    bf16* MB1 = (bf16*)alloc((size_t)NM * 256 * 2);
    bf16* MB2 = (bf16*)alloc((size_t)NM * 256 * 2);
    bf16* MB3 = (bf16*)alloc((size_t)NM * 256 * 2);
    int* degcur = (int*)alloc((size_t)2 * (NM + NU) * 4);
    int* deg_m = degcur;
    int* deg_u = degcur + NM;
    int* cur_m = degcur + NM + NU;
    int* cur_u = degcur + 2 * NM + NU;
    int* off_m = (int*)alloc((size_t)NM * 4);
    int* off_u = (int*)alloc((size_t)NU * 4);
    int2* rec_m = (int2*)alloc((size_t)(E + 4) * 8);
    int2* rec_u = (int2*)alloc((size_t)(E + 4) * 8);
    int* bsum_m = (int*)alloc(64 * 4);
    int* bsum_u = (int*)alloc(64 * 4);
    unsigned short* wt_l1um_l = (unsigned short*)alloc(256 * 256 * 2);
    unsigned short* wt_l1mu_r = (unsigned short*)alloc(256 * 256 * 2);
    unsigned short* wt_l1um_r = (unsigned short*)alloc(256 * 256 * 2);
    unsigned short* wt_l1mu_l = (unsigned short*)alloc(256 * 256 * 2);
    unsigned short* wt_c_user  = (unsigned short*)alloc(512 * 64 * 2);
    unsigned short* wt_c_movie = (unsigned short*)alloc(512 * 64 * 2);
    float* bc_user  = (float*)alloc(512 * 4);
    float* bc_movie = (float*)alloc(512 * 4);
    if (off > ws_size) return;

    float* out_u = (float*)d_out;
    float* out_m = out_u + (size_t)NU * 64;

    const int FB = 256;

    // ---- weight prep ----
    TxArgs tx;
    tx.src[0] = F(L1UM+0); tx.dst[0] = wt_l1um_l;
    tx.src[1] = F(L1MU+2); tx.dst[1] = wt_l1mu_r;
    tx.src[2] = F(L1UM+2); tx.dst[2] = wt_l1um_r;
    tx.src[3] = F(L1MU+0); tx.dst[3] = wt_l1mu_l;
    txp_kernel<<<dim3(64, 4), 256, 0, stream>>>(tx);
    // user: cols 0-255 = W_user@l0um_Wl (xl_u0), 256-511 = W_user@l0mu_Wr (xr_u0)
    cw_kernel<<<CDIV(512 * 64 + 512, 256), 256, 0, stream>>>(
        W_user, b_user, F(L0UM+0), F(L0UM+1), F(L0MU+2), F(L0MU+3), wt_c_user, bc_user);
    // movie: cols 0-255 = W_movie@l0um_Wr (xr_m0), 256-511 = W_movie@l0mu_Wl (xl_m0)
    cw_kernel<<<CDIV(512 * 64 + 512, 256), 256, 0, stream>>>(
        W_movie, b_movie, F(L0UM+2), F(L0UM+3), F(L0MU+0), F(L0MU+1), wt_c_movie, bc_movie);

    // ---- CSR build (both directions) ----
    fill_i32<<<CDIV(2 * (NM + NU), FB), FB, 0, stream>>>(degcur, 0, (long)2 * (NM + NU));
    hist2_kernel<<<CDIV(2 * E, FB), FB, 0, stream>>>(ei_um + E, ei_mu + E, deg_m, deg_u, E);
    const int nbm = CDIV(NM, SCAN_T * SCAN_E), nbu = CDIV(NU, SCAN_T * SCAN_E);
    scan1_dual_kernel<<<dim3(max(nbm, nbu), 2), SCAN_T, 0, stream>>>(
        deg_m, off_m, bsum_m, NM, deg_u, off_u, bsum_u, NU);
    scan2_dual_kernel<<<1, 128, 0, stream>>>(bsum_m, nbm, bsum_u, nbu);
    scan3_dual_kernel<<<dim3(CDIV(max(NM, NU), FB), 2), FB, 0, stream>>>(
        off_m, bsum_m, NM, off_u, bsum_u, NU);
    csr_fill2_kernel<<<CDIV(2 * E, FB), FB, 0, stream>>>(
        ei_um, ei_um + E, ea_um, off_m, cur_m, rec_m,
        ei_mu, ei_mu + E, ea_mu, off_u, cur_u, rec_u, E);

    // ---- layer-0 projections (phase-0 folded): gather f32 emb, K=64 ----
    gemm256_kernel<64, true><<<CDIV(NU, 64) * 2, 256, 0, stream>>>(
        user_emb, user_ids, wt_c_user, wt_c_user + 256 * 64, bc_user, bc_user + 256,
        (unsigned short*)UB1, (unsigned short*)UB2, NU);          // xl_u0, xr_u0
    gemm256_kernel<64, true><<<CDIV(NM, 64) * 2, 256, 0, stream>>>(
        movie_emb, movie_ids, wt_c_movie, wt_c_movie + 256 * 64, bc_movie, bc_movie + 256,
        (unsigned short*)MB1, (unsigned short*)MB3, NM);          // xr_m0, xl_m0

    // ---- layer 0 fused GAT ----
    gat_fused_kernel<true><<<CDIV(NM, 4), 256, 0, stream>>>(
        deg_m, off_m, rec_m, UB1, MB1, F(L0UM+4), F(L0UM+5), F(L0UM+6), g0m, be0m, MB2, NM);  // xm1
    gat_fused_kernel<true><<<CDIV(NU, 4), 256, 0, stream>>>(
        deg_u, off_u, rec_u, MB3, UB2, F(L0MU+4), F(L0MU+5), F(L0MU+6), g0u, be0u, UB1, NU);  // xu1

    // ---- layer-1 projections ----
    gemm256_kernel<256, false><<<CDIV(NU, 64) * 2, 256, 0, stream>>>(
        (unsigned short*)UB1, nullptr, wt_l1um_l, wt_l1mu_r, F(L1UM+1), F(L1MU+3),
        (unsigned short*)UB2, (unsigned short*)UB3, NU);          // xl_u1, xr_u1
    gemm256_kernel<256, false><<<CDIV(NM, 64) * 2, 256, 0, stream>>>(
        (unsigned short*)MB2, nullptr, wt_l1um_r, wt_l1mu_l, F(L1UM+3), F(L1MU+1),
        (unsigned short*)MB1, (unsigned short*)MB3, NM);          // xr_m1, xl_m1

    // ---- layer 1 fused GAT ----
    gat_fused_kernel<false><<<CDIV(NM, 4), 256, 0, stream>>>(
        deg_m, off_m, rec_m, UB2, MB1, F(L1UM+4), F(L1UM+5), F(L1UM+6), g1m, be1m, out_m, NM);
    gat_fused_kernel<false><<<CDIV(NU, 4), 256, 0, stream>>>(
        deg_u, off_u, rec_u, MB3, UB3, F(L1MU+4), F(L1MU+5), F(L1MU+6), g1u, be1u, out_u, NU);
}

// Round 10
// 416.761 us; speedup vs baseline: 1.6981x; 1.0007x over previous
//
#include <hip/hip_runtime.h>
#include <hip/hip_bf16.h>
#include <cstdint>

typedef __hip_bfloat16 bf16;
#define CDIV(a,b) (((a)+(b)-1)/(b))

typedef __attribute__((ext_vector_type(8))) short short8;
typedef __attribute__((ext_vector_type(8))) unsigned short usht8;
typedef __attribute__((ext_vector_type(4))) float f32x4v;

struct us4 { unsigned short x, y, z, w; };

// ---------------- device helpers ----------------
__device__ __forceinline__ float lrelu02(float x) { return fmaxf(x, 0.f) + 0.2f * fminf(x, 0.f); }

__device__ __forceinline__ float b2f(unsigned short u) {
    return __uint_as_float((unsigned)u << 16);
}
// f32 -> bf16 bits, round-to-nearest-even
__device__ __forceinline__ unsigned short f2b(float f) {
    unsigned u = __float_as_uint(f);
    unsigned r = u + 0x7FFFu + ((u >> 16) & 1u);
    return (unsigned short)(r >> 16);
}

// swizzled LDS index (ushort units) for [row][32] tiles, 8-elem granularity
__device__ __forceinline__ int swz(int row, int kg) {
    return row * 32 + (kg ^ ((row >> 1) & 3)) * 8;
}

// ---------------- fill ----------------
__global__ void fill_i32(int* __restrict__ p, int v, long n) {
    long i = (long)blockIdx.x * blockDim.x + threadIdx.x;
    long st = (long)gridDim.x * blockDim.x;
    for (; i < n; i += st) p[i] = v;
}

// ---------------- CSR build (both directions fused) ----------------
__global__ void hist2_kernel(const int* __restrict__ edm, const int* __restrict__ edu,
                             int* __restrict__ deg_m, int* __restrict__ deg_u, int E) {
    int e = blockIdx.x * blockDim.x + threadIdx.x;
    if (e < E) atomicAdd(&deg_m[edm[e]], 1);
    else if (e < 2 * E) atomicAdd(&deg_u[edu[e - E]], 1);
}

#define SCAN_T 256
#define SCAN_E 16
__global__ void __launch_bounds__(SCAN_T) scan1_dual_kernel(
    const int* __restrict__ deg0, int* __restrict__ off0, int* __restrict__ bsum0, int n0,
    const int* __restrict__ deg1, int* __restrict__ off1, int* __restrict__ bsum1, int n1)
{
    const int* deg = blockIdx.y ? deg1 : deg0;
    int* off  = blockIdx.y ? off1 : off0;
    int* bsum = blockIdx.y ? bsum1 : bsum0;
    const int n = blockIdx.y ? n1 : n0;

    __shared__ int lds[SCAN_T];
    const int tb = blockIdx.x * (SCAN_T * SCAN_E) + threadIdx.x * SCAN_E;
    int v[SCAN_E];
    int tot = 0;
#pragma unroll
    for (int j = 0; j < SCAN_E; ++j) {
        v[j] = (tb + j < n) ? deg[tb + j] : 0;
        tot += v[j];
    }
    lds[threadIdx.x] = tot;
    __syncthreads();
    for (int s = 1; s < SCAN_T; s <<= 1) {
        int t = (threadIdx.x >= s) ? lds[threadIdx.x - s] : 0;
        __syncthreads();
        lds[threadIdx.x] += t;
        __syncthreads();
    }
    int run = (threadIdx.x > 0) ? lds[threadIdx.x - 1] : 0;
#pragma unroll
    for (int j = 0; j < SCAN_E; ++j) {
        if (tb + j < n) off[tb + j] = run;
        run += v[j];
    }
    if (threadIdx.x == SCAN_T - 1) bsum[blockIdx.x] = lds[SCAN_T - 1];
}
__global__ void scan2_dual_kernel(int* __restrict__ bm, int nbm, int* __restrict__ bu, int nbu) {
    int t = threadIdx.x & 63;
    int* b = (threadIdx.x >= 64) ? bu : bm;
    int nb = (threadIdx.x >= 64) ? nbu : nbm;
    int orig = (t < nb) ? b[t] : 0;
    int v = orig;
    for (int s = 1; s < 64; s <<= 1) {
        int u = __shfl_up(v, s);
        if (t >= s) v += u;
    }
    if (t < nb) b[t] = v - orig;
}
__global__ void scan3_dual_kernel(int* __restrict__ off0, const int* __restrict__ bsum0, int n0,
                                  int* __restrict__ off1, const int* __restrict__ bsum1, int n1) {
    int* off = blockIdx.y ? off1 : off0;
    const int* bsum = blockIdx.y ? bsum1 : bsum0;
    const int n = blockIdx.y ? n1 : n0;
    int i = blockIdx.x * blockDim.x + threadIdx.x;
    if (i < n) off[i] += bsum[i / (SCAN_T * SCAN_E)];
}

__global__ void csr_fill2_kernel(
    const int* __restrict__ esm, const int* __restrict__ edm, const float* __restrict__ eam,
    const int* __restrict__ offm, int* __restrict__ curm, int2* __restrict__ recm,
    const int* __restrict__ esu, const int* __restrict__ edu, const float* __restrict__ eau,
    const int* __restrict__ offu, int* __restrict__ curu, int2* __restrict__ recu, int E)
{
    int e = blockIdx.x * blockDim.x + threadIdx.x;
    if (e < E) {
        int d = edm[e];
        int r = atomicAdd(&curm[d], 1);
        int2 q; q.x = esm[e]; q.y = __float_as_int(eam[e]);
        recm[offm[d] + r] = q;
    } else if (e < 2 * E) {
        e -= E;
        int d = edu[e];
        int r = atomicAdd(&curu[d], 1);
        int2 q; q.x = esu[e]; q.y = __float_as_int(eau[e]);
        recu[offu[d] + r] = q;
    }
}

// ---------------- weight transpose+convert: W[K][N] f32 -> Wt[N][K] bf16 ----
struct TxArgs {
    const float* src[4];
    unsigned short* dst[4];
};
__global__ void txp_kernel(TxArgs a) {
    const int m = blockIdx.y;
    const int K = 256, N = 256;
    const long total = (long)K * N;
    const float* __restrict__ s = a.src[m];
    unsigned short* __restrict__ d = a.dst[m];
    for (long i = (long)blockIdx.x * blockDim.x + threadIdx.x; i < total;
         i += (long)gridDim.x * blockDim.x) {
        int k = (int)(i >> 8), nn = (int)(i & 255);
        d[(long)nn * K + k] = f2b(s[i]);
    }
}

// ---------------- combine phase-0 + layer-0 weights (all affine) ----------
__global__ void cw_kernel(const float* __restrict__ Wu, const float* __restrict__ bu,
                          const float* __restrict__ Wa, const float* __restrict__ ba,
                          const float* __restrict__ Wb, const float* __restrict__ bb,
                          unsigned short* __restrict__ wt, float* __restrict__ bc)
{
    int tid = blockIdx.x * blockDim.x + threadIdx.x;
    if (tid < 512 * 64) {
        int nn = tid >> 6, k = tid & 63;
        const float* Ws = (nn < 256) ? Wa : Wb;
        int nc = nn & 255;
        float s = 0.f;
        for (int c = 0; c < 64; ++c) s = fmaf(Wu[k * 64 + c], Ws[c * 256 + nc], s);
        wt[nn * 64 + k] = f2b(s);
    } else if (tid < 512 * 64 + 512) {
        int nn = tid - 512 * 64;
        const float* Ws = (nn < 256) ? Wa : Wb;
        const float* bs = (nn < 256) ? ba : bb;
        int nc = nn & 255;
        float s = bs[nc];
        for (int c = 0; c < 64; ++c) s = fmaf(bu[c], Ws[c * 256 + nc], s);
        bc[nn] = s;
    }
}

// ---------------- MFMA GEMM, paired column-halves, LDS-staged epilogue ----
template<int K, bool GATHER>
__global__ void __launch_bounds__(256) gemm256_kernel(
    const void* __restrict__ Asrc, const int* __restrict__ ids,
    const unsigned short* __restrict__ Wt0, const unsigned short* __restrict__ Wt1,
    const float* __restrict__ bias0, const float* __restrict__ bias1,
    unsigned short* __restrict__ Y0, unsigned short* __restrict__ Y1, int n)
{
    const int t = threadIdx.x;
    const int wid = t >> 6, lane = t & 63;
    const int half = blockIdx.x & 1;
    const int row0 = (blockIdx.x >> 1) * 64;
    const unsigned short* __restrict__ Wt = half ? Wt1 : Wt0;
    const float* __restrict__ bias = half ? bias1 : bias0;
    unsigned short* __restrict__ Y = half ? Y1 : Y0;

    __shared__ unsigned short SMEM[64 * 32 + 256 * 32];   // As | Ws; reused as C-stage
    unsigned short* As = SMEM;
    unsigned short* Ws = SMEM + 64 * 32;

    f32x4v acc[4][4];
#pragma unroll
    for (int rt = 0; rt < 4; ++rt)
#pragma unroll
        for (int ct = 0; ct < 4; ++ct) acc[rt][ct] = (f32x4v){0.f, 0.f, 0.f, 0.f};

    const int r_st = t >> 2, kg_st = t & 3;
    const int grow = row0 + r_st;
    long abase = 0;
    if (grow < n) abase = GATHER ? (long)ids[grow] * K : (long)grow * K;

    for (int kt = 0; kt < K / 32; ++kt) {
        usht8 av = (usht8)0;
        if (grow < n) {
            if (GATHER) {
                const float* p = (const float*)Asrc + abase + kt * 32 + kg_st * 8;
#pragma unroll
                for (int j = 0; j < 8; ++j) av[j] = f2b(p[j]);
            } else {
                av = *(const usht8*)((const unsigned short*)Asrc + abase + kt * 32 + kg_st * 8);
            }
        }
        *(usht8*)&As[swz(r_st, kg_st)] = av;
#pragma unroll
        for (int i = 0; i < 4; ++i) {
            int idx = t + i * 256;
            int c = idx >> 2, kg = idx & 3;
            *(usht8*)&Ws[swz(c, kg)] = *(const usht8*)&Wt[(long)c * K + kt * 32 + kg * 8];
        }
        __syncthreads();

        const int kgrp = lane >> 4;
        short8 af[4];
#pragma unroll
        for (int rt = 0; rt < 4; ++rt)
            af[rt] = *(const short8*)&As[swz(rt * 16 + (lane & 15), kgrp)];
#pragma unroll
        for (int ct = 0; ct < 4; ++ct) {
            int col = wid * 64 + ct * 16 + (lane & 15);
            short8 bfr = *(const short8*)&Ws[swz(col, kgrp)];
#pragma unroll
            for (int rt = 0; rt < 4; ++rt)
                acc[rt][ct] = __builtin_amdgcn_mfma_f32_16x16x32_bf16(af[rt], bfr, acc[rt][ct], 0, 0, 0);
        }
        __syncthreads();
    }

    // ---- epilogue: stage bf16 C tile in LDS, store dense 16B chunks ----
    float bb[4];
#pragma unroll
    for (int ct = 0; ct < 4; ++ct) bb[ct] = bias[wid * 64 + ct * 16 + (lane & 15)];

#pragma unroll
    for (int rh = 0; rh < 2; ++rh) {                // rows rh*32 .. rh*32+31
#pragma unroll
        for (int rt = rh * 2; rt < rh * 2 + 2; ++rt) {
#pragma unroll
            for (int ct = 0; ct < 4; ++ct) {
                int col = wid * 64 + ct * 16 + (lane & 15);
#pragma unroll
                for (int j = 0; j < 4; ++j) {
                    int rl = rt * 16 + (lane >> 4) * 4 + j - rh * 32;
                    SMEM[rl * 256 + col] = f2b(acc[rt][ct][j] + bb[ct]);
                }
            }
        }
        __syncthreads();
#pragma unroll
        for (int i = 0; i < 4; ++i) {
            int idx = t + i * 256;
            int rl = idx >> 5, cseg = (idx & 31) * 8;
            int row = row0 + rh * 32 + rl;
            if (row < n)
                *(usht8*)&Y[(long)row * 256 + cseg] = *(const usht8*)&SMEM[rl * 256 + cseg];
        }
        __syncthreads();
    }
}

// ---------------- fused GATv2 layer (head-split lanes, grid-stride) -------
// lane = h*16 + q; lane owns channels c = h*64 + q*4 .. +3.
// Grid-stride over dsts: per-wave constants (We/att/bias/g/be) hoisted.
// Defer-max online softmax: batched 4-edge logits, thresholded rescale.
template<bool CONCAT>
__global__ void __launch_bounds__(256) gat_fused_kernel(
    const int* __restrict__ deg, const int* __restrict__ off,
    const int2* __restrict__ rec,
    const bf16* __restrict__ xl, const bf16* __restrict__ xr,
    const float* __restrict__ We, const float* __restrict__ att,
    const float* __restrict__ bias,
    const float* __restrict__ g, const float* __restrict__ be,
    void* __restrict__ yout, int n)
{
    const int lane = threadIdx.x & 63;
    const int q = lane & 15;
    const int c0 = ((lane >> 4) << 6) + (q << 2);   // h*64 + q*4
    const int wid0 = blockIdx.x * 4 + (threadIdx.x >> 6);
    const int wstride = gridDim.x * 4;

    // ---- wave-invariant constants ----
    float4 We4 = *(const float4*)(We + c0);
    float4 att4 = *(const float4*)(att + c0);
    float att06[4], att04[4];
#pragma unroll
    for (int i = 0; i < 4; ++i) {
        att06[i] = 0.6f * (&att4.x)[i];
        att04[i] = 0.4f * (&att4.x)[i];
    }
    const int ec = CONCAT ? c0 : (q << 2);
    float4 bi = *(const float4*)(bias + ec);
    float4 gg = *(const float4*)(g + ec);
    float4 bb = *(const float4*)(be + ec);

    const unsigned short* __restrict__ xlp = (const unsigned short*)xl;

    for (int d = wid0; d < n; d += wstride) {
        us4 xrv = *(const us4*)((const unsigned short*)xr + (long)d * 256 + c0);
        float xr4[4] = {b2f(xrv.x), b2f(xrv.y), b2f(xrv.z), b2f(xrv.w)};

        float m = -1e30f, den = 0.f;
        float acc[4] = {0.f, 0.f, 0.f, 0.f};

        const int dg = deg[d], o0 = off[d];

        for (int base = 0; base < dg; base += 64) {
            int2 r;
            if (base + lane < dg) r = rec[o0 + base + lane];
            else { r.x = 0; r.y = 0; }
            const int cnt = min(dg - base, 64);
            for (int j = 0; j < cnt; j += 4) {
                us4 xvA[4];
                int aB[4];
#pragma unroll
                for (int u = 0; u < 4; ++u) {
                    int s = __builtin_amdgcn_readlane(r.x, j + u);   // SGPR broadcast
                    aB[u] = __builtin_amdgcn_readlane(r.y, j + u);
                    xvA[u] = *(const us4*)(xlp + (long)s * 256 + c0);
                }
                float l[4], xvf[4][4];
#pragma unroll
                for (int u = 0; u < 4; ++u) {
                    xvf[u][0] = b2f(xvA[u].x); xvf[u][1] = b2f(xvA[u].y);
                    xvf[u][2] = b2f(xvA[u].z); xvf[u][3] = b2f(xvA[u].w);
                    const float a = __int_as_float(aB[u]);
                    float part = 0.f;
#pragma unroll
                    for (int i = 0; i < 4; ++i) {
                        float t = xvf[u][i] + fmaf(a, (&We4.x)[i], xr4[i]);
                        part = fmaf(att06[i], t, part);          // lrelu*att =
                        part = fmaf(att04[i], fabsf(t), part);   // 0.6at + 0.4a|t|
                    }
#pragma unroll
                    for (int st = 1; st < 16; st <<= 1) part += __shfl_xor(part, st);
                    l[u] = (j + u < cnt) ? part : -1e30f;
                }
                // thresholded rescale (defer-max, exact): p bounded by e^8
                float bmax = fmaxf(fmaxf(l[0], l[1]), fmaxf(l[2], l[3]));
                if (__any(bmax > m + 8.f)) {
                    float mn = fmaxf(m, bmax);
                    float sc = __expf(m - mn);
                    den *= sc;
#pragma unroll
                    for (int i = 0; i < 4; ++i) acc[i] *= sc;
                    m = mn;
                }
#pragma unroll
                for (int u = 0; u < 4; ++u) {
                    float p = __expf(l[u] - m);
                    den += p;
#pragma unroll
                    for (int i = 0; i < 4; ++i) acc[i] = fmaf(p, xvf[u][i], acc[i]);
                }
            }
        }

        const float id = 1.f / (den + 1e-16f);
        if (CONCAT) {
            float v[4], s1 = 0.f, s2 = 0.f;
#pragma unroll
            for (int i = 0; i < 4; ++i) {
                v[i] = fmaf(acc[i], id, (&bi.x)[i]);
                s1 += v[i]; s2 = fmaf(v[i], v[i], s2);
            }
#pragma unroll
            for (int st = 1; st < 64; st <<= 1) {
                s1 += __shfl_xor(s1, st);
                s2 += __shfl_xor(s2, st);
            }
            float mean = s1 * (1.f / 256.f);
            float var = s2 * (1.f / 256.f) - mean * mean;
            float rr = rsqrtf(var + 1e-5f);
            us4 o;
            o.x = f2b(lrelu02(fmaf((&gg.x)[0] * rr, v[0] - mean, (&bb.x)[0])));
            o.y = f2b(lrelu02(fmaf((&gg.x)[1] * rr, v[1] - mean, (&bb.x)[1])));
            o.z = f2b(lrelu02(fmaf((&gg.x)[2] * rr, v[2] - mean, (&bb.x)[2])));
            o.w = f2b(lrelu02(fmaf((&gg.x)[3] * rr, v[3] - mean, (&bb.x)[3])));
            *(us4*)((unsigned short*)yout + (long)d * 256 + c0) = o;
        } else {
            float vh[4];
#pragma unroll
            for (int i = 0; i < 4; ++i) vh[i] = acc[i] * id;
#pragma unroll
            for (int st = 16; st < 64; st <<= 1)
#pragma unroll
                for (int i = 0; i < 4; ++i) vh[i] += __shfl_xor(vh[i], st);
            float v[4], s1 = 0.f, s2 = 0.f;
#pragma unroll
            for (int i = 0; i < 4; ++i) {
                v[i] = fmaf(0.25f, vh[i], (&bi.x)[i]);
                s1 += v[i]; s2 = fmaf(v[i], v[i], s2);
            }
#pragma unroll
            for (int st = 1; st < 16; st <<= 1) {
                s1 += __shfl_xor(s1, st);
                s2 += __shfl_xor(s2, st);
            }
            float mean = s1 * (1.f / 64.f);
            float var = s2 * (1.f / 64.f) - mean * mean;
            float rr = rsqrtf(var + 1e-5f);
            if (lane < 16) {
                float4 o;
                o.x = lrelu02(fmaf((&gg.x)[0] * rr, v[0] - mean, (&bb.x)[0]));
                o.y = lrelu02(fmaf((&gg.x)[1] * rr, v[1] - mean, (&bb.x)[1]));
                o.z = lrelu02(fmaf((&gg.x)[2] * rr, v[2] - mean, (&bb.x)[2]));
                o.w = lrelu02(fmaf((&gg.x)[3] * rr, v[3] - mean, (&bb.x)[3]));
                *(float4*)((float*)yout + (long)d * 64 + (q << 2)) = o;
            }
        }
    }
}

// ---------------- host orchestration ----------------
extern "C" void kernel_launch(void* const* d_in, const int* in_sizes, int n_in,
                              void* d_out, int out_size, void* d_ws, size_t ws_size,
                              hipStream_t stream)
{
    auto F = [&](int i) { return (const float*)d_in[i]; };
    auto I = [&](int i) { return (const int*)d_in[i]; };

    const int NU = in_sizes[0];
    const int NM = in_sizes[1];
    const int E  = in_sizes[2] / 2;

    const int* user_ids  = I(0);
    const int* movie_ids = I(1);
    const int* ei_um = I(2);
    const int* ei_mu = I(3);
    const float* ea_um = F(4);
    const float* ea_mu = F(5);
    const float* user_emb  = F(6);
    const float* movie_emb = F(7);
    const float* W_user = F(8),  *b_user = F(9);
    const float* W_movie = F(10), *b_movie = F(11);
    const int L0UM = 12, L0MU = 19, L1UM = 26, L1MU = 33;
    const float* g0u = F(40), *be0u = F(41);
    const float* g0m = F(42), *be0m = F(43);
    const float* g1u = F(44), *be1u = F(45);
    const float* g1m = F(46), *be1m = F(47);

    // ---- workspace layout ----
    char* w = (char*)d_ws;
    size_t off = 0;
    auto alloc = [&](size_t bytes) -> void* {
        void* p = w + off;
        off = (off + bytes + 255) & ~(size_t)255;
        return p;
    };
    bf16* UB1 = (bf16*)alloc((size_t)NU * 256 * 2);
    bf16* UB2 = (bf16*)alloc((size_t)NU * 256 * 2);
    bf16* UB3 = (bf16*)alloc((size_t)NU * 256 * 2);
    bf16* MB1 = (bf16*)alloc((size_t)NM * 256 * 2);
    bf16* MB2 = (bf16*)alloc((size_t)NM * 256 * 2);
    bf16* MB3 = (bf16*)alloc((size_t)NM * 256 * 2);
    int* degcur = (int*)alloc((size_t)2 * (NM + NU) * 4);
    int* deg_m = degcur;
    int* deg_u = degcur + NM;
    int* cur_m = degcur + NM + NU;
    int* cur_u = degcur + 2 * NM + NU;
    int* off_m = (int*)alloc((size_t)NM * 4);
    int* off_u = (int*)alloc((size_t)NU * 4);
    int2* rec_m = (int2*)alloc((size_t)(E + 4) * 8);
    int2* rec_u = (int2*)alloc((size_t)(E + 4) * 8);
    int* bsum_m = (int*)alloc(64 * 4);
    int* bsum_u = (int*)alloc(64 * 4);
    unsigned short* wt_l1um_l = (unsigned short*)alloc(256 * 256 * 2);
    unsigned short* wt_l1mu_r = (unsigned short*)alloc(256 * 256 * 2);
    unsigned short* wt_l1um_r = (unsigned short*)alloc(256 * 256 * 2);
    unsigned short* wt_l1mu_l = (unsigned short*)alloc(256 * 256 * 2);
    unsigned short* wt_c_user  = (unsigned short*)alloc(512 * 64 * 2);
    unsigned short* wt_c_movie = (unsigned short*)alloc(512 * 64 * 2);
    float* bc_user  = (float*)alloc(512 * 4);
    float* bc_movie = (float*)alloc(512 * 4);
    if (off > ws_size) return;

    float* out_u = (float*)d_out;
    float* out_m = out_u + (size_t)NU * 64;

    const int FB = 256;

    // ---- weight prep ----
    TxArgs tx;
    tx.src[0] = F(L1UM+0); tx.dst[0] = wt_l1um_l;
    tx.src[1] = F(L1MU+2); tx.dst[1] = wt_l1mu_r;
    tx.src[2] = F(L1UM+2); tx.dst[2] = wt_l1um_r;
    tx.src[3] = F(L1MU+0); tx.dst[3] = wt_l1mu_l;
    txp_kernel<<<dim3(64, 4), 256, 0, stream>>>(tx);
    cw_kernel<<<CDIV(512 * 64 + 512, 256), 256, 0, stream>>>(
        W_user, b_user, F(L0UM+0), F(L0UM+1), F(L0MU+2), F(L0MU+3), wt_c_user, bc_user);
    cw_kernel<<<CDIV(512 * 64 + 512, 256), 256, 0, stream>>>(
        W_movie, b_movie, F(L0UM+2), F(L0UM+3), F(L0MU+0), F(L0MU+1), wt_c_movie, bc_movie);

    // ---- CSR build (both directions) ----
    fill_i32<<<CDIV(2 * (NM + NU), FB), FB, 0, stream>>>(degcur, 0, (long)2 * (NM + NU));
    hist2_kernel<<<CDIV(2 * E, FB), FB, 0, stream>>>(ei_um + E, ei_mu + E, deg_m, deg_u, E);
    const int nbm = CDIV(NM, SCAN_T * SCAN_E), nbu = CDIV(NU, SCAN_T * SCAN_E);
    scan1_dual_kernel<<<dim3(max(nbm, nbu), 2), SCAN_T, 0, stream>>>(
        deg_m, off_m, bsum_m, NM, deg_u, off_u, bsum_u, NU);
    scan2_dual_kernel<<<1, 128, 0, stream>>>(bsum_m, nbm, bsum_u, nbu);
    scan3_dual_kernel<<<dim3(CDIV(max(NM, NU), FB), 2), FB, 0, stream>>>(
        off_m, bsum_m, NM, off_u, bsum_u, NU);
    csr_fill2_kernel<<<CDIV(2 * E, FB), FB, 0, stream>>>(
        ei_um, ei_um + E, ea_um, off_m, cur_m, rec_m,
        ei_mu, ei_mu + E, ea_mu, off_u, cur_u, rec_u, E);

    // ---- layer-0 projections (phase-0 folded): gather f32 emb, K=64 ----
    gemm256_kernel<64, true><<<CDIV(NU, 64) * 2, 256, 0, stream>>>(
        user_emb, user_ids, wt_c_user, wt_c_user + 256 * 64, bc_user, bc_user + 256,
        (unsigned short*)UB1, (unsigned short*)UB2, NU);          // xl_u0, xr_u0
    gemm256_kernel<64, true><<<CDIV(NM, 64) * 2, 256, 0, stream>>>(
        movie_emb, movie_ids, wt_c_movie, wt_c_movie + 256 * 64, bc_movie, bc_movie + 256,
        (unsigned short*)MB1, (unsigned short*)MB3, NM);          // xr_m0, xl_m0

    auto ggrid = [&](int n) { int b = CDIV(n, 4); if (b > 2048) b = 2048; return dim3((unsigned)b); };

    // ---- layer 0 fused GAT ----
    gat_fused_kernel<true><<<ggrid(NM), 256, 0, stream>>>(
        deg_m, off_m, rec_m, UB1, MB1, F(L0UM+4), F(L0UM+5), F(L0UM+6), g0m, be0m, MB2, NM);  // xm1
    gat_fused_kernel<true><<<ggrid(NU), 256, 0, stream>>>(
        deg_u, off_u, rec_u, MB3, UB2, F(L0MU+4), F(L0MU+5), F(L0MU+6), g0u, be0u, UB1, NU);  // xu1

    // ---- layer-1 projections ----
    gemm256_kernel<256, false><<<CDIV(NU, 64) * 2, 256, 0, stream>>>(
        (unsigned short*)UB1, nullptr, wt_l1um_l, wt_l1mu_r, F(L1UM+1), F(L1MU+3),
        (unsigned short*)UB2, (unsigned short*)UB3, NU);          // xl_u1, xr_u1
    gemm256_kernel<256, false><<<CDIV(NM, 64) * 2, 256, 0, stream>>>(
        (unsigned short*)MB2, nullptr, wt_l1um_r, wt_l1mu_l, F(L1UM+3), F(L1MU+1),
        (unsigned short*)MB1, (unsigned short*)MB3, NM);          // xr_m1, xl_m1

    // ---- layer 1 fused GAT ----
    gat_fused_kernel<false><<<ggrid(NM), 256, 0, stream>>>(
        deg_m, off_m, rec_m, UB2, MB1, F(L1UM+4), F(L1UM+5), F(L1UM+6), g1m, be1m, out_m, NM);
    gat_fused_kernel<false><<<ggrid(NU), 256, 0, stream>>>(
        deg_u, off_u, rec_u, MB3, UB3, F(L1MU+4), F(L1MU+5), F(L1MU+6), g1u, be1u, out_u, NU);
}

// Round 12
// 396.938 us; speedup vs baseline: 1.7829x; 1.0499x over previous
//
#include <hip/hip_runtime.h>
#include <hip/hip_bf16.h>
#include <cstdint>

typedef __hip_bfloat16 bf16;
#define CDIV(a,b) (((a)+(b)-1)/(b))

typedef __attribute__((ext_vector_type(8))) short short8;
typedef __attribute__((ext_vector_type(8))) unsigned short usht8;
typedef __attribute__((ext_vector_type(4))) float f32x4v;

struct us4 { unsigned short x, y, z, w; };

// ---------------- device helpers ----------------
__device__ __forceinline__ float lrelu02(float x) { return fmaxf(x, 0.f) + 0.2f * fminf(x, 0.f); }

__device__ __forceinline__ float b2f(unsigned short u) {
    return __uint_as_float((unsigned)u << 16);
}
__device__ __forceinline__ unsigned short f2b(float f) {
    unsigned u = __float_as_uint(f);
    unsigned r = u + 0x7FFFu + ((u >> 16) & 1u);
    return (unsigned short)(r >> 16);
}
__device__ __forceinline__ int swz(int row, int kg) {
    return row * 32 + (kg ^ ((row >> 1) & 3)) * 8;
}

// ---------------- fill ----------------
__global__ void fill_i32(int* __restrict__ p, int v, long n) {
    long i = (long)blockIdx.x * blockDim.x + threadIdx.x;
    long st = (long)gridDim.x * blockDim.x;
    for (; i < n; i += st) p[i] = v;
}

// ---------------- CSR build (both directions fused) ----------------
__global__ void hist2_kernel(const int* __restrict__ edm, const int* __restrict__ edu,
                             int* __restrict__ deg_m, int* __restrict__ deg_u, int E) {
    int e = blockIdx.x * blockDim.x + threadIdx.x;
    if (e < E) atomicAdd(&deg_m[edm[e]], 1);
    else if (e < 2 * E) atomicAdd(&deg_u[edu[e - E]], 1);
}

#define SCAN_T 256
#define SCAN_E 16
__global__ void __launch_bounds__(SCAN_T) scan1_dual_kernel(
    const int* __restrict__ deg0, int* __restrict__ off0, int* __restrict__ bsum0, int n0,
    const int* __restrict__ deg1, int* __restrict__ off1, int* __restrict__ bsum1, int n1)
{
    const int* deg = blockIdx.y ? deg1 : deg0;
    int* off  = blockIdx.y ? off1 : off0;
    int* bsum = blockIdx.y ? bsum1 : bsum0;
    const int n = blockIdx.y ? n1 : n0;

    __shared__ int lds[SCAN_T];
    const int tb = blockIdx.x * (SCAN_T * SCAN_E) + threadIdx.x * SCAN_E;
    int v[SCAN_E];
    int tot = 0;
#pragma unroll
    for (int j = 0; j < SCAN_E; ++j) {
        v[j] = (tb + j < n) ? deg[tb + j] : 0;
        tot += v[j];
    }
    lds[threadIdx.x] = tot;
    __syncthreads();
    for (int s = 1; s < SCAN_T; s <<= 1) {
        int t = (threadIdx.x >= s) ? lds[threadIdx.x - s] : 0;
        __syncthreads();
        lds[threadIdx.x] += t;
        __syncthreads();
    }
    int run = (threadIdx.x > 0) ? lds[threadIdx.x - 1] : 0;
#pragma unroll
    for (int j = 0; j < SCAN_E; ++j) {
        if (tb + j < n) off[tb + j] = run;
        run += v[j];
    }
    if (threadIdx.x == SCAN_T - 1) bsum[blockIdx.x] = lds[SCAN_T - 1];
}
__global__ void scan2_dual_kernel(int* __restrict__ bm, int nbm, int* __restrict__ bu, int nbu) {
    int t = threadIdx.x & 63;
    int* b = (threadIdx.x >= 64) ? bu : bm;
    int nb = (threadIdx.x >= 64) ? nbu : nbm;
    int orig = (t < nb) ? b[t] : 0;
    int v = orig;
    for (int s = 1; s < 64; s <<= 1) {
        int u = __shfl_up(v, s);
        if (t >= s) v += u;
    }
    if (t < nb) b[t] = v - orig;
}
__global__ void scan3_dual_kernel(int* __restrict__ off0, const int* __restrict__ bsum0, int n0,
                                  int* __restrict__ off1, const int* __restrict__ bsum1, int n1) {
    int* off = blockIdx.y ? off1 : off0;
    const int* bsum = blockIdx.y ? bsum1 : bsum0;
    const int n = blockIdx.y ? n1 : n0;
    int i = blockIdx.x * blockDim.x + threadIdx.x;
    if (i < n) off[i] += bsum[i / (SCAN_T * SCAN_E)];
}

__global__ void csr_fill2_kernel(
    const int* __restrict__ esm, const int* __restrict__ edm, const float* __restrict__ eam,
    const int* __restrict__ offm, int* __restrict__ curm, int2* __restrict__ recm,
    const int* __restrict__ esu, const int* __restrict__ edu, const float* __restrict__ eau,
    const int* __restrict__ offu, int* __restrict__ curu, int2* __restrict__ recu, int E)
{
    int e = blockIdx.x * blockDim.x + threadIdx.x;
    if (e < E) {
        int d = edm[e];
        int r = atomicAdd(&curm[d], 1);
        int2 q; q.x = esm[e]; q.y = __float_as_int(eam[e]);
        recm[offm[d] + r] = q;
    } else if (e < 2 * E) {
        e -= E;
        int d = edu[e];
        int r = atomicAdd(&curu[d], 1);
        int2 q; q.x = esu[e]; q.y = __float_as_int(eau[e]);
        recu[offu[d] + r] = q;
    }
}

// ---------------- weight transpose+convert ----------------
struct TxArgs {
    const float* src[4];
    unsigned short* dst[4];
};
__global__ void txp_kernel(TxArgs a) {
    const int m = blockIdx.y;
    const int K = 256, N = 256;
    const long total = (long)K * N;
    const float* __restrict__ s = a.src[m];
    unsigned short* __restrict__ d = a.dst[m];
    for (long i = (long)blockIdx.x * blockDim.x + threadIdx.x; i < total;
         i += (long)gridDim.x * blockDim.x) {
        int k = (int)(i >> 8), nn = (int)(i & 255);
        d[(long)nn * K + k] = f2b(s[i]);
    }
}

// ---------------- combine phase-0 + layer-0 weights ----------
__global__ void cw_kernel(const float* __restrict__ Wu, const float* __restrict__ bu,
                          const float* __restrict__ Wa, const float* __restrict__ ba,
                          const float* __restrict__ Wb, const float* __restrict__ bb,
                          unsigned short* __restrict__ wt, float* __restrict__ bc)
{
    int tid = blockIdx.x * blockDim.x + threadIdx.x;
    if (tid < 512 * 64) {
        int nn = tid >> 6, k = tid & 63;
        const float* Ws = (nn < 256) ? Wa : Wb;
        int nc = nn & 255;
        float s = 0.f;
        for (int c = 0; c < 64; ++c) s = fmaf(Wu[k * 64 + c], Ws[c * 256 + nc], s);
        wt[nn * 64 + k] = f2b(s);
    } else if (tid < 512 * 64 + 512) {
        int nn = tid - 512 * 64;
        const float* Ws = (nn < 256) ? Wa : Wb;
        const float* bs = (nn < 256) ? ba : bb;
        int nc = nn & 255;
        float s = bs[nc];
        for (int c = 0; c < 64; ++c) s = fmaf(bu[c], Ws[c * 256 + nc], s);
        bc[nn] = s;
    }
}

// ---------------- merged MFMA GEMM (two independent node-type segments) ----
struct GemmP {
    const void* A; const int* ids;
    const unsigned short* Wt0; const unsigned short* Wt1;
    const float* b0; const float* b1;
    unsigned short* Y0; unsigned short* Y1;
    int n;
};
template<int K, bool GATHER>
__global__ void __launch_bounds__(256) gemm2_kernel(GemmP P0, GemmP P1, int nblk0)
{
    const bool seg1 = (int)blockIdx.x >= nblk0;
    const GemmP P = seg1 ? P1 : P0;
    const int lb = seg1 ? (int)blockIdx.x - nblk0 : (int)blockIdx.x;

    const int t = threadIdx.x;
    const int wid = t >> 6, lane = t & 63;
    const int half = lb & 1;
    const int row0 = (lb >> 1) * 64;
    const unsigned short* Wt = half ? P.Wt1 : P.Wt0;
    const float* bias = half ? P.b1 : P.b0;
    unsigned short* Y = half ? P.Y1 : P.Y0;
    const int n = P.n;

    __shared__ unsigned short SMEM[64 * 32 + 256 * 32];   // As | Ws; reused as C-stage
    unsigned short* As = SMEM;
    unsigned short* Ws = SMEM + 64 * 32;

    f32x4v acc[4][4];
#pragma unroll
    for (int rt = 0; rt < 4; ++rt)
#pragma unroll
        for (int ct = 0; ct < 4; ++ct) acc[rt][ct] = (f32x4v){0.f, 0.f, 0.f, 0.f};

    const int r_st = t >> 2, kg_st = t & 3;
    const int grow = row0 + r_st;
    long abase = 0;
    if (grow < n) abase = GATHER ? (long)P.ids[grow] * K : (long)grow * K;

    for (int kt = 0; kt < K / 32; ++kt) {
        usht8 av = (usht8)0;
        if (grow < n) {
            if (GATHER) {
                const float* p = (const float*)P.A + abase + kt * 32 + kg_st * 8;
#pragma unroll
                for (int j = 0; j < 8; ++j) av[j] = f2b(p[j]);
            } else {
                av = *(const usht8*)((const unsigned short*)P.A + abase + kt * 32 + kg_st * 8);
            }
        }
        *(usht8*)&As[swz(r_st, kg_st)] = av;
#pragma unroll
        for (int i = 0; i < 4; ++i) {
            int idx = t + i * 256;
            int c = idx >> 2, kg = idx & 3;
            *(usht8*)&Ws[swz(c, kg)] = *(const usht8*)&Wt[(long)c * K + kt * 32 + kg * 8];
        }
        __syncthreads();

        const int kgrp = lane >> 4;
        short8 af[4];
#pragma unroll
        for (int rt = 0; rt < 4; ++rt)
            af[rt] = *(const short8*)&As[swz(rt * 16 + (lane & 15), kgrp)];
#pragma unroll
        for (int ct = 0; ct < 4; ++ct) {
            int col = wid * 64 + ct * 16 + (lane & 15);
            short8 bfr = *(const short8*)&Ws[swz(col, kgrp)];
#pragma unroll
            for (int rt = 0; rt < 4; ++rt)
                acc[rt][ct] = __builtin_amdgcn_mfma_f32_16x16x32_bf16(af[rt], bfr, acc[rt][ct], 0, 0, 0);
        }
        __syncthreads();
    }

    // ---- epilogue: stage bf16 C tile in LDS, store dense 16B chunks ----
    float bb[4];
#pragma unroll
    for (int ct = 0; ct < 4; ++ct) bb[ct] = bias[wid * 64 + ct * 16 + (lane & 15)];

#pragma unroll
    for (int rh = 0; rh < 2; ++rh) {
#pragma unroll
        for (int rt = rh * 2; rt < rh * 2 + 2; ++rt) {
#pragma unroll
            for (int ct = 0; ct < 4; ++ct) {
                int col = wid * 64 + ct * 16 + (lane & 15);
#pragma unroll
                for (int j = 0; j < 4; ++j) {
                    int rl = rt * 16 + (lane >> 4) * 4 + j - rh * 32;
                    SMEM[rl * 256 + col] = f2b(acc[rt][ct][j] + bb[ct]);
                }
            }
        }
        __syncthreads();
#pragma unroll
        for (int i = 0; i < 4; ++i) {
            int idx = t + i * 256;
            int rl = idx >> 5, cseg = (idx & 31) * 8;
            int row = row0 + rh * 32 + rl;
            if (row < n)
                *(usht8*)&Y[(long)row * 256 + cseg] = *(const usht8*)&SMEM[rl * 256 + cseg];
        }
        __syncthreads();
    }
}

// ---------------- merged fused GATv2 layer (two independent segments) -----
// lane = h*16 + q; lane owns channels c = h*64 + q*4 .. +3. One wave per dst
// (per-dst blocks -> HW backfills wave slots). exp2-domain defer-max softmax.
// NOTE: read/write buffer sets of the two segments MUST be disjoint — block
// execution order within one launch is undefined.
struct GatP {
    const int* deg; const int* off; const int2* rec;
    const unsigned short* xl; const unsigned short* xr;
    const float* We; const float* att; const float* bias;
    const float* g; const float* be;
    void* y;
    int n;
};
template<bool CONCAT>
__global__ void __launch_bounds__(256) gat2_kernel(GatP P0, GatP P1, int nblk0)
{
    const bool seg1 = (int)blockIdx.x >= nblk0;
    const GatP P = seg1 ? P1 : P0;
    const int lb = seg1 ? (int)blockIdx.x - nblk0 : (int)blockIdx.x;
    const int lane = threadIdx.x & 63;
    const int d = lb * 4 + (threadIdx.x >> 6);
    if (d >= P.n) return;

    const int q = lane & 15;
    const int c0 = ((lane >> 4) << 6) + (q << 2);   // h*64 + q*4
    const float LOG2E = 1.4426950408889634f;

    // ---- per-wave constants (logits carried in log2 domain) ----
    float4 We4 = *(const float4*)(P.We + c0);
    float4 att4 = *(const float4*)(P.att + c0);
    float att06[4], att04[4];
#pragma unroll
    for (int i = 0; i < 4; ++i) {
        att06[i] = 0.6f * LOG2E * (&att4.x)[i];
        att04[i] = 0.4f * LOG2E * (&att4.x)[i];
    }
    const int ec = CONCAT ? c0 : (q << 2);
    float4 bi = *(const float4*)(P.bias + ec);
    float4 gg = *(const float4*)(P.g + ec);
    float4 bb = *(const float4*)(P.be + ec);

    us4 xrv = *(const us4*)(P.xr + (long)d * 256 + c0);
    float xr4[4] = {b2f(xrv.x), b2f(xrv.y), b2f(xrv.z), b2f(xrv.w)};

    float m = -1e30f, den = 0.f;
    float acc[4] = {0.f, 0.f, 0.f, 0.f};

    const int dg = P.deg[d], o0 = P.off[d];
    const unsigned short* xlp = P.xl;

    for (int base = 0; base < dg; base += 64) {
        int2 r;
        if (base + lane < dg) r = P.rec[o0 + base + lane];
        else { r.x = 0; r.y = 0; }
        const int cnt = min(dg - base, 64);
        for (int j = 0; j < cnt; j += 4) {
            us4 xvA[4];
            int aB[4];
#pragma unroll
            for (int u = 0; u < 4; ++u) {
                int s = __builtin_amdgcn_readlane(r.x, j + u);   // SGPR broadcast
                aB[u] = __builtin_amdgcn_readlane(r.y, j + u);
                xvA[u] = *(const us4*)(xlp + (long)s * 256 + c0);
            }
            float l[4], xvf[4][4];
#pragma unroll
            for (int u = 0; u < 4; ++u) {
                xvf[u][0] = b2f(xvA[u].x); xvf[u][1] = b2f(xvA[u].y);
                xvf[u][2] = b2f(xvA[u].z); xvf[u][3] = b2f(xvA[u].w);
                const float a = __int_as_float(aB[u]);
                float part = 0.f;
#pragma unroll
                for (int i = 0; i < 4; ++i) {
                    float t = xvf[u][i] + fmaf(a, (&We4.x)[i], xr4[i]);
                    part = fmaf(att06[i], t, part);          // log2e*lrelu*att
                    part = fmaf(att04[i], fabsf(t), part);
                }
#pragma unroll
                for (int st = 1; st < 16; st <<= 1) part += __shfl_xor(part, st);
                l[u] = (j + u < cnt) ? part : -1e30f;
            }
            // defer-max rescale (exact): p bounded by 2^11.54 = e^8
            float bmax = fmaxf(fmaxf(l[0], l[1]), fmaxf(l[2], l[3]));
            if (__any(bmax > m + 11.5415603f)) {
                float mn = fmaxf(m, bmax);
                float sc = exp2f(m - mn);
                den *= sc;
#pragma unroll
                for (int i = 0; i < 4; ++i) acc[i] *= sc;
                m = mn;
            }
#pragma unroll
            for (int u = 0; u < 4; ++u) {
                float p = exp2f(l[u] - m);
                den += p;
#pragma unroll
                for (int i = 0; i < 4; ++i) acc[i] = fmaf(p, xvf[u][i], acc[i]);
            }
        }
    }

    const float id = 1.f / (den + 1e-16f);
    if (CONCAT) {
        float v[4], s1 = 0.f, s2 = 0.f;
#pragma unroll
        for (int i = 0; i < 4; ++i) {
            v[i] = fmaf(acc[i], id, (&bi.x)[i]);
            s1 += v[i]; s2 = fmaf(v[i], v[i], s2);
        }
#pragma unroll
        for (int st = 1; st < 64; st <<= 1) {
            s1 += __shfl_xor(s1, st);
            s2 += __shfl_xor(s2, st);
        }
        float mean = s1 * (1.f / 256.f);
        float var = s2 * (1.f / 256.f) - mean * mean;
        float rr = rsqrtf(var + 1e-5f);
        us4 o;
        o.x = f2b(lrelu02(fmaf((&gg.x)[0] * rr, v[0] - mean, (&bb.x)[0])));
        o.y = f2b(lrelu02(fmaf((&gg.x)[1] * rr, v[1] - mean, (&bb.x)[1])));
        o.z = f2b(lrelu02(fmaf((&gg.x)[2] * rr, v[2] - mean, (&bb.x)[2])));
        o.w = f2b(lrelu02(fmaf((&gg.x)[3] * rr, v[3] - mean, (&bb.x)[3])));
        *(us4*)((unsigned short*)P.y + (long)d * 256 + c0) = o;
    } else {
        float vh[4];
#pragma unroll
        for (int i = 0; i < 4; ++i) vh[i] = acc[i] * id;
#pragma unroll
        for (int st = 16; st < 64; st <<= 1)
#pragma unroll
            for (int i = 0; i < 4; ++i) vh[i] += __shfl_xor(vh[i], st);
        float v[4], s1 = 0.f, s2 = 0.f;
#pragma unroll
        for (int i = 0; i < 4; ++i) {
            v[i] = fmaf(0.25f, vh[i], (&bi.x)[i]);
            s1 += v[i]; s2 = fmaf(v[i], v[i], s2);
        }
#pragma unroll
        for (int st = 1; st < 16; st <<= 1) {
            s1 += __shfl_xor(s1, st);
            s2 += __shfl_xor(s2, st);
        }
        float mean = s1 * (1.f / 64.f);
        float var = s2 * (1.f / 64.f) - mean * mean;
        float rr = rsqrtf(var + 1e-5f);
        if (lane < 16) {
            float4 o;
            o.x = lrelu02(fmaf((&gg.x)[0] * rr, v[0] - mean, (&bb.x)[0]));
            o.y = lrelu02(fmaf((&gg.x)[1] * rr, v[1] - mean, (&bb.x)[1]));
            o.z = lrelu02(fmaf((&gg.x)[2] * rr, v[2] - mean, (&bb.x)[2]));
            o.w = lrelu02(fmaf((&gg.x)[3] * rr, v[3] - mean, (&bb.x)[3]));
            *(float4*)((float*)P.y + (long)d * 64 + (q << 2)) = o;
        }
    }
}

// ---------------- host orchestration ----------------
extern "C" void kernel_launch(void* const* d_in, const int* in_sizes, int n_in,
                              void* d_out, int out_size, void* d_ws, size_t ws_size,
                              hipStream_t stream)
{
    auto F = [&](int i) { return (const float*)d_in[i]; };
    auto I = [&](int i) { return (const int*)d_in[i]; };

    const int NU = in_sizes[0];
    const int NM = in_sizes[1];
    const int E  = in_sizes[2] / 2;

    const int* user_ids  = I(0);
    const int* movie_ids = I(1);
    const int* ei_um = I(2);
    const int* ei_mu = I(3);
    const float* ea_um = F(4);
    const float* ea_mu = F(5);
    const float* user_emb  = F(6);
    const float* movie_emb = F(7);
    const float* W_user = F(8),  *b_user = F(9);
    const float* W_movie = F(10), *b_movie = F(11);
    const int L0UM = 12, L0MU = 19, L1UM = 26, L1MU = 33;
    const float* g0u = F(40), *be0u = F(41);
    const float* g0m = F(42), *be0m = F(43);
    const float* g1u = F(44), *be1u = F(45);
    const float* g1m = F(46), *be1m = F(47);

    // ---- workspace layout ----
    char* w = (char*)d_ws;
    size_t off = 0;
    auto alloc = [&](size_t bytes) -> void* {
        void* p = w + off;
        off = (off + bytes + 255) & ~(size_t)255;
        return p;
    };
    bf16* UB1 = (bf16*)alloc((size_t)NU * 256 * 2);
    bf16* UB2 = (bf16*)alloc((size_t)NU * 256 * 2);
    bf16* UB3 = (bf16*)alloc((size_t)NU * 256 * 2);
    bf16* MB1 = (bf16*)alloc((size_t)NM * 256 * 2);
    bf16* MB2 = (bf16*)alloc((size_t)NM * 256 * 2);
    bf16* MB3 = (bf16*)alloc((size_t)NM * 256 * 2);
    int* degcur = (int*)alloc((size_t)2 * (NM + NU) * 4);
    int* deg_m = degcur;
    int* deg_u = degcur + NM;
    int* cur_m = degcur + NM + NU;
    int* cur_u = degcur + 2 * NM + NU;
    int* off_m = (int*)alloc((size_t)NM * 4);
    int* off_u = (int*)alloc((size_t)NU * 4);
    int2* rec_m = (int2*)alloc((size_t)(E + 4) * 8);
    int2* rec_u = (int2*)alloc((size_t)(E + 4) * 8);
    int* bsum_m = (int*)alloc(64 * 4);
    int* bsum_u = (int*)alloc(64 * 4);
    unsigned short* wt_l1um_l = (unsigned short*)alloc(256 * 256 * 2);
    unsigned short* wt_l1mu_r = (unsigned short*)alloc(256 * 256 * 2);
    unsigned short* wt_l1um_r = (unsigned short*)alloc(256 * 256 * 2);
    unsigned short* wt_l1mu_l = (unsigned short*)alloc(256 * 256 * 2);
    unsigned short* wt_c_user  = (unsigned short*)alloc(512 * 64 * 2);
    unsigned short* wt_c_movie = (unsigned short*)alloc(512 * 64 * 2);
    float* bc_user  = (float*)alloc(512 * 4);
    float* bc_movie = (float*)alloc(512 * 4);
    if (off > ws_size) return;

    float* out_u = (float*)d_out;
    float* out_m = out_u + (size_t)NU * 64;

    const int FB = 256;

    // ---- weight prep ----
    TxArgs tx;
    tx.src[0] = F(L1UM+0); tx.dst[0] = wt_l1um_l;
    tx.src[1] = F(L1MU+2); tx.dst[1] = wt_l1mu_r;
    tx.src[2] = F(L1UM+2); tx.dst[2] = wt_l1um_r;
    tx.src[3] = F(L1MU+0); tx.dst[3] = wt_l1mu_l;
    txp_kernel<<<dim3(64, 4), 256, 0, stream>>>(tx);
    cw_kernel<<<CDIV(512 * 64 + 512, 256), 256, 0, stream>>>(
        W_user, b_user, F(L0UM+0), F(L0UM+1), F(L0MU+2), F(L0MU+3), wt_c_user, bc_user);
    cw_kernel<<<CDIV(512 * 64 + 512, 256), 256, 0, stream>>>(
        W_movie, b_movie, F(L0UM+2), F(L0UM+3), F(L0MU+0), F(L0MU+1), wt_c_movie, bc_movie);

    // ---- CSR build (both directions) ----
    fill_i32<<<CDIV(2 * (NM + NU), FB), FB, 0, stream>>>(degcur, 0, (long)2 * (NM + NU));
    hist2_kernel<<<CDIV(2 * E, FB), FB, 0, stream>>>(ei_um + E, ei_mu + E, deg_m, deg_u, E);
    const int nbm = CDIV(NM, SCAN_T * SCAN_E), nbu = CDIV(NU, SCAN_T * SCAN_E);
    scan1_dual_kernel<<<dim3(max(nbm, nbu), 2), SCAN_T, 0, stream>>>(
        deg_m, off_m, bsum_m, NM, deg_u, off_u, bsum_u, NU);
    scan2_dual_kernel<<<1, 128, 0, stream>>>(bsum_m, nbm, bsum_u, nbu);
    scan3_dual_kernel<<<dim3(CDIV(max(NM, NU), FB), 2), FB, 0, stream>>>(
        off_m, bsum_m, NM, off_u, bsum_u, NU);
    csr_fill2_kernel<<<CDIV(2 * E, FB), FB, 0, stream>>>(
        ei_um, ei_um + E, ea_um, off_m, cur_m, rec_m,
        ei_mu, ei_mu + E, ea_mu, off_u, cur_u, rec_u, E);

    // ---- layer-0 projections (merged movie+user; phase-0 folded, K=64) ----
    {
        GemmP PM{movie_emb, movie_ids, wt_c_movie, wt_c_movie + 256 * 64,
                 bc_movie, bc_movie + 256, (unsigned short*)MB1, (unsigned short*)MB3, NM};
        GemmP PU{user_emb, user_ids, wt_c_user, wt_c_user + 256 * 64,
                 bc_user, bc_user + 256, (unsigned short*)UB1, (unsigned short*)UB2, NU};
        int nM = CDIV(NM, 64) * 2, nU = CDIV(NU, 64) * 2;
        gemm2_kernel<64, true><<<nM + nU, 256, 0, stream>>>(PM, PU, nM);
        // MB1=xr_m0, MB3=xl_m0, UB1=xl_u0, UB2=xr_u0
    }

    // ---- layer 0 fused GAT (merged; writes {MB2, UB3} disjoint from reads) ----
    {
        GatP PM{deg_m, off_m, rec_m, (const unsigned short*)UB1, (const unsigned short*)MB1,
                F(L0UM+4), F(L0UM+5), F(L0UM+6), g0m, be0m, MB2, NM};          // xm1
        GatP PU{deg_u, off_u, rec_u, (const unsigned short*)MB3, (const unsigned short*)UB2,
                F(L0MU+4), F(L0MU+5), F(L0MU+6), g0u, be0u, UB3, NU};          // xu1 -> UB3
        gat2_kernel<true><<<CDIV(NM, 4) + CDIV(NU, 4), 256, 0, stream>>>(PM, PU, CDIV(NM, 4));
    }

    // ---- layer-1 projections (merged; reads {MB2,UB3}, writes {MB1,MB3,UB1,UB2}) ----
    {
        GemmP PM{(unsigned short*)MB2, nullptr, wt_l1um_r, wt_l1mu_l,
                 F(L1UM+3), F(L1MU+1), (unsigned short*)MB1, (unsigned short*)MB3, NM};
        GemmP PU{(unsigned short*)UB3, nullptr, wt_l1um_l, wt_l1mu_r,
                 F(L1UM+1), F(L1MU+3), (unsigned short*)UB1, (unsigned short*)UB2, NU};
        int nM = CDIV(NM, 64) * 2, nU = CDIV(NU, 64) * 2;
        gemm2_kernel<256, false><<<nM + nU, 256, 0, stream>>>(PM, PU, nM);
        // MB1=xr_m1, MB3=xl_m1, UB1=xl_u1, UB2=xr_u1
    }

    // ---- layer 1 fused GAT (merged; reads {UB1,MB1,MB3,UB2}, writes d_out) ----
    {
        GatP PM{deg_m, off_m, rec_m, (const unsigned short*)UB1, (const unsigned short*)MB1,
                F(L1UM+4), F(L1UM+5), F(L1UM+6), g1m, be1m, out_m, NM};
        GatP PU{deg_u, off_u, rec_u, (const unsigned short*)MB3, (const unsigned short*)UB2,
                F(L1MU+4), F(L1MU+5), F(L1MU+6), g1u, be1u, out_u, NU};
        gat2_kernel<false><<<CDIV(NM, 4) + CDIV(NU, 4), 256, 0, stream>>>(PM, PU, CDIV(NM, 4));
    }
}